// Round 1
// baseline (205.509 us; speedup 1.0000x reference)
//
#include <hip/hip_runtime.h>
#include <stdint.h>

// MAB block: B=32, N=512, D=512, H=8, dh=64.  M = B*N = 16384.
// scale = 1/sqrt(512)
#define SCALE_ 0.044194173824159216f

typedef __attribute__((ext_vector_type(8))) short bf16x8;   // 8 bf16 = 4 VGPR (guide-verified frag type)
typedef __attribute__((ext_vector_type(4))) float f32x4;

__device__ __forceinline__ ushort f2b(float f) {
  union { float f; uint32_t u; } v; v.f = f;
  return (ushort)((v.u + 0x7fffu + ((v.u >> 16) & 1u)) >> 16);  // RNE
}

__device__ __forceinline__ void gld16(void* lds, const void* g) {
  __builtin_amdgcn_global_load_lds(
      (const __attribute__((address_space(1))) uint32_t*)g,
      (__attribute__((address_space(3))) uint32_t*)lds, 16, 0, 0);
}

// ---------------- fp32 -> bf16 convert (Q, K, 6 weights) ----------------
__global__ __launch_bounds__(256)
void k_cvt(const float* __restrict__ Q, const float* __restrict__ K,
           const float* __restrict__ w0, const float* __restrict__ w1,
           const float* __restrict__ w2, const float* __restrict__ w3,
           const float* __restrict__ w4, const float* __restrict__ w5,
           ushort* __restrict__ Qb, ushort* __restrict__ Kb, ushort* __restrict__ Wb)
{
  const long long NQ = 8388608LL, NW = 262144LL;
  long long i = ((long long)blockIdx.x * 256 + threadIdx.x) * 4;
  const float* src; ushort* dst; long long off;
  if (i < NQ)        { src = Q; dst = Qb; off = i; }
  else if (i < 2*NQ) { src = K; dst = Kb; off = i - NQ; }
  else {
    long long j = i - 2*NQ; int seg = (int)(j / NW); off = j - (long long)seg * NW;
    switch (seg) { case 0: src = w0; break; case 1: src = w1; break; case 2: src = w2; break;
                   case 3: src = w3; break; case 4: src = w4; break; default: src = w5; }
    dst = Wb + (size_t)seg * NW;
  }
  float4 v = *(const float4*)(src + off);
  ushort4 o = make_ushort4(f2b(v.x), f2b(v.y), f2b(v.z), f2b(v.w));
  *(ushort4*)(dst + off) = o;
}

// ---------------- GEMM C = A(bf16,[M,512]) @ Bw(bf16,[512,512])^T, NT form ----------------
// m97 structure: 128x128 tile, BK=32, 4 waves, global_load_lds width 16, 2 barriers/K-step.
// EPI: 0 = bias->bf16   1 = Q + (acc+bias) -> f32 out + bf16 copy   2 = relu->bf16   3 = out += acc+bias
template<int EPI>
__device__ __forceinline__ void gemm_body(const ushort* __restrict__ A, const ushort* __restrict__ Bw,
                                          const float* __restrict__ bias, const float* __restrict__ extra,
                                          float* __restrict__ outf, ushort* __restrict__ outb,
                                          ushort* At, ushort* Bt, int m0, int n0)
{
  const int t = threadIdx.x;
  const int w = t >> 6, lane = t & 63;
  const int wr = w >> 1, wc = w & 1;
  const int rA = lane & 15, g = lane >> 4;
  // staging chunks: tile [128 rows][32 k] bf16 = 512 x 16B chunks; 2 per thread
  const int c1 = w*64 + lane, c2 = c1 + 256;
  const ushort* gA1 = A  + (size_t)(m0 + (c1 >> 2))*512 + (c1 & 3)*8;
  const ushort* gA2 = A  + (size_t)(m0 + (c2 >> 2))*512 + (c2 & 3)*8;
  const ushort* gB1 = Bw + (size_t)(n0 + (c1 >> 2))*512 + (c1 & 3)*8;
  const ushort* gB2 = Bw + (size_t)(n0 + (c2 >> 2))*512 + (c2 & 3)*8;
  f32x4 acc[4][4] = {};
  for (int kt = 0; kt < 512; kt += 32) {
    gld16((char*)At +        w*1024, gA1 + kt);
    gld16((char*)At + 4096 + w*1024, gA2 + kt);
    gld16((char*)Bt +        w*1024, gB1 + kt);
    gld16((char*)Bt + 4096 + w*1024, gB2 + kt);
    __syncthreads();                      // vmcnt drained by compiler before barrier
    bf16x8 af[4], bfr[4];
#pragma unroll
    for (int m = 0; m < 4; m++) af[m]  = *(const bf16x8*)(At + (wr*64 + m*16 + rA)*32 + g*8);
#pragma unroll
    for (int n = 0; n < 4; n++) bfr[n] = *(const bf16x8*)(Bt + (wc*64 + n*16 + rA)*32 + g*8);
#pragma unroll
    for (int m = 0; m < 4; m++)
#pragma unroll
      for (int n = 0; n < 4; n++)
        acc[m][n] = __builtin_amdgcn_mfma_f32_16x16x32_bf16(af[m], bfr[n], acc[m][n], 0, 0, 0);
    __syncthreads();                      // protect LDS before next stage
  }
#pragma unroll
  for (int m = 0; m < 4; m++)
#pragma unroll
    for (int n = 0; n < 4; n++) {
      int col = n0 + wc*64 + n*16 + rA;
      float bb = bias[col];
#pragma unroll
      for (int r = 0; r < 4; r++) {
        int row = m0 + wr*64 + m*16 + g*4 + r;   // C/D: col=lane&15, row=(lane>>4)*4+reg
        size_t idx = (size_t)row*512 + col;
        float v = acc[m][n][r] + bb;
        if (EPI == 0)      outb[idx] = f2b(v);
        else if (EPI == 1) { float o = extra[idx] + v; outf[idx] = o; outb[idx] = f2b(o); }
        else if (EPI == 2) outb[idx] = f2b(v > 0.f ? v : 0.f);
        else               outf[idx] += v;
      }
    }
}

template<int EPI>
__global__ __launch_bounds__(256)
void k_gemm(const ushort* __restrict__ A, const ushort* __restrict__ Bw,
            const float* __restrict__ bias, const float* __restrict__ extra,
            float* __restrict__ outf, ushort* __restrict__ outb)
{
  __shared__ ushort At[128*32], Bt[128*32];
  gemm_body<EPI>(A, Bw, bias, extra, outf, outb, At, Bt, blockIdx.x*128, blockIdx.y*128);
}

// fused q/k/v projection: z selects (A, W, bias, out slice); Wq,Wk,Wv and qp,kp,vp are consecutive
__global__ __launch_bounds__(256)
void k_gemm_qkv(const ushort* __restrict__ Qb, const ushort* __restrict__ Kb,
                const ushort* __restrict__ Wb, const float* __restrict__ bq,
                const float* __restrict__ bk, const float* __restrict__ bvv,
                ushort* __restrict__ out)
{
  __shared__ ushort At[128*32], Bt[128*32];
  int z = blockIdx.z;
  const ushort* A = (z == 0) ? Qb : Kb;
  const float* bias = (z == 0) ? bq : ((z == 1) ? bk : bvv);
  gemm_body<0>(A, Wb + (size_t)z*262144, bias, nullptr, nullptr,
               out + (size_t)z*8388608, At, Bt, blockIdx.x*128, blockIdx.y*128);
}

// ---------------- transpose vp[b,k,h*64+d] -> vpT[(b,h,d), k] ----------------
__global__ __launch_bounds__(256)
void k_tr(const ushort* __restrict__ vp, ushort* __restrict__ vpT)
{
  __shared__ ushort tile[128][72];        // +8 pad: conflict-light column reads
  int bid = blockIdx.x;                   // bh*4 + kb
  int bh = bid >> 2, kb = bid & 3;
  int b = bh >> 3, h = bh & 7;
  int t = threadIdx.x;
#pragma unroll
  for (int i = 0; i < 4; i++) {           // load [128 k][64 d]
    int c = i*256 + t; int row = c >> 3, cg = c & 7;
    *(bf16x8*)&tile[row][cg*8] =
        *(const bf16x8*)(vp + (size_t)(b*512 + kb*128 + row)*512 + h*64 + cg*8);
  }
  __syncthreads();
#pragma unroll
  for (int i = 0; i < 4; i++) {           // store [64 d][128 k]
    int c = i*256 + t; int d = c >> 4, kg = c & 15;
    union { ushort s[8]; bf16x8 v; } tmp;
#pragma unroll
    for (int j = 0; j < 8; j++) tmp.s[j] = tile[kg*8 + j][d];
    *(bf16x8*)(vpT + (size_t)(bh*64 + d)*512 + kb*128 + kg*8) = tmp.v;
  }
}

// ---------------- K2: column-softmax denominators: zinv[bh,k] = 1/sum_q exp(s*scale) ----------------
// block = (b,h,khalf); 4 waves, each owns 64 k-cols of the 256-col half.
__global__ __launch_bounds__(256)
void k_z(const ushort* __restrict__ qp, const ushort* __restrict__ kp, float* __restrict__ zinv)
{
  __shared__ ushort kt[256*64];   // 32KB, rows = k-index, cols = d  (source-swizzled)
  __shared__ ushort qt[64*64];    //  8KB, rows = q,      cols = d  (source-swizzled)
  int bid = blockIdx.x;
  int bh = bid >> 1, kh = bid & 1;
  int b = bh >> 3, h = bh & 7;
  int t = threadIdx.x, w = t >> 6, lane = t & 63;
  int rA = lane & 15, g = lane >> 4;
  const ushort* kbase = kp + (size_t)(b*512 + kh*256)*512 + h*64;
  const ushort* qbase = qp + (size_t)(b*512)*512 + h*64;
#pragma unroll
  for (int i = 0; i < 8; i++) {   // stage kt: 2048 chunks (row has 8 x 16B slots; src col-group = slot^(row&7))
    int c = i*256 + w*64 + lane;
    int row = c >> 3, sl = c & 7, cg = sl ^ (row & 7);
    gld16((char*)kt + (i*256 + w*64)*16, kbase + (size_t)row*512 + cg*8);
  }
  float Zacc[4] = {0.f, 0.f, 0.f, 0.f};
  for (int qb = 0; qb < 8; qb++) {
    __syncthreads();              // prev-iter qt readers done (iter0: no-op)
    {
      int c = w*64 + lane;
      int row = c >> 3, sl = c & 7, cg = sl ^ (row & 7);
      gld16((char*)qt + w*1024, qbase + (size_t)(qb*64 + row)*512 + cg*8);
      int c2 = 256 + c;
      int row2 = c2 >> 3, sl2 = c2 & 7, cg2 = sl2 ^ (row2 & 7);
      gld16((char*)qt + 4096 + w*1024, qbase + (size_t)(qb*64 + row2)*512 + cg2*8);
    }
    __syncthreads();              // qt (and kt on iter0) ready
    f32x4 acc[4][4] = {};
#pragma unroll
    for (int ks = 0; ks < 2; ks++) {
      bf16x8 af[4], bfr[4];
#pragma unroll
      for (int m = 0; m < 4; m++) {
        int row = m*16 + rA;
        af[m] = *(const bf16x8*)(qt + row*64 + (((ks*4 + g) ^ (row & 7))*8));
      }
#pragma unroll
      for (int n = 0; n < 4; n++) {
        int row = w*64 + n*16 + rA;
        bfr[n] = *(const bf16x8*)(kt + row*64 + (((ks*4 + g) ^ (row & 7))*8));
      }
#pragma unroll
      for (int m = 0; m < 4; m++)
#pragma unroll
        for (int n = 0; n < 4; n++)
          acc[m][n] = __builtin_amdgcn_mfma_f32_16x16x32_bf16(af[m], bfr[n], acc[m][n], 0, 0, 0);
    }
#pragma unroll
    for (int m = 0; m < 4; m++)
#pragma unroll
      for (int n = 0; n < 4; n++) {
        float s = 0.f;
#pragma unroll
        for (int r = 0; r < 4; r++) s += __expf(acc[m][n][r] * SCALE_);
        Zacc[n] += s;
      }
  }
#pragma unroll
  for (int n = 0; n < 4; n++) {   // reduce over the 4 row-groups (lanes l, l^16, l^32, l^48)
    float v = Zacc[n];
    v += __shfl_xor(v, 16);
    v += __shfl_xor(v, 32);
    if (lane < 16) zinv[(size_t)bh*512 + kh*256 + w*64 + n*16 + lane] = 1.0f / v;
  }
}

// ---------------- K3: attn[b,q,h,d] = sum_k exp(s)*zinv[k] * v[k,d] (s recomputed) ----------------
// block = (b,h,qhalf); wave owns 64 q rows x all 64 d. k chunks of 32.
__global__ __launch_bounds__(256)
void k_attn(const ushort* __restrict__ qp, const ushort* __restrict__ kp,
            const ushort* __restrict__ vpT, const float* __restrict__ zinv,
            ushort* __restrict__ attn)
{
  __shared__ ushort qt[256*64];    // 32KB (source-swizzled)
  __shared__ ushort ktile[32*64];  //  4KB rows=k cols=d (source-swizzled)
  __shared__ ushort vt[64*32];     //  4KB rows=d cols=k (source-swizzled, slot^((d>>1)&3))
  __shared__ ushort P[4][64*40];   // 20KB wave-private P, padded stride 40 (conflict-free)
  __shared__ float zl[512];        //  2KB
  int bid = blockIdx.x;
  int bh = bid >> 1, qh = bid & 1;
  int b = bh >> 3, h = bh & 7;
  int t = threadIdx.x, w = t >> 6, lane = t & 63;
  int rA = lane & 15, g = lane >> 4;
  const ushort* qbase = qp + (size_t)(b*512 + qh*256)*512 + h*64;
  const ushort* kbase = kp + (size_t)(b*512)*512 + h*64;
  const ushort* vbase = vpT + (size_t)bh*64*512;
  ushort* Pw = &P[w][0];
#pragma unroll
  for (int i = 0; i < 8; i++) {    // stage qt once (reused for all 16 k-chunks)
    int c = i*256 + w*64 + lane;
    int row = c >> 3, sl = c & 7, cg = sl ^ (row & 7);
    gld16((char*)qt + (i*256 + w*64)*16, qbase + (size_t)row*512 + cg*8);
  }
  zl[t]       = zinv[(size_t)bh*512 + t];
  zl[t + 256] = zinv[(size_t)bh*512 + t + 256];
  f32x4 oacc[4][4] = {};
  for (int kc = 0; kc < 16; kc++) {
    __syncthreads();               // prev-chunk ktile/vt readers done
    {
      int c = w*64 + lane;
      int row = c >> 3, sl = c & 7, cg = sl ^ (row & 7);
      gld16((char*)ktile + w*1024, kbase + (size_t)(kc*32 + row)*512 + cg*8);
      int rowv = c >> 2, slv = c & 3, cgv = slv ^ ((rowv >> 1) & 3);
      gld16((char*)vt + w*1024, vbase + (size_t)rowv*512 + kc*32 + cgv*8);
    }
    __syncthreads();               // staged (vmcnt drained; covers qt/zl on first iter)
    // ---- s = q @ k^T for [64 q x 32 k] (this wave's q rows) ----
    f32x4 sacc[4][2] = {};
#pragma unroll
    for (int ks = 0; ks < 2; ks++) {
      bf16x8 af[4], bfr[2];
#pragma unroll
      for (int m = 0; m < 4; m++) {
        int row = w*64 + m*16 + rA;
        af[m] = *(const bf16x8*)(qt + row*64 + (((ks*4 + g) ^ (row & 7))*8));
      }
#pragma unroll
      for (int kn = 0; kn < 2; kn++) {
        int row = kn*16 + rA;
        bfr[kn] = *(const bf16x8*)(ktile + row*64 + (((ks*4 + g) ^ (row & 7))*8));
      }
#pragma unroll
      for (int m = 0; m < 4; m++)
#pragma unroll
        for (int kn = 0; kn < 2; kn++)
          sacc[m][kn] = __builtin_amdgcn_mfma_f32_16x16x32_bf16(af[m], bfr[kn], sacc[m][kn], 0, 0, 0);
    }
    // ---- P = exp(s*scale) * zinv[k] -> wave-private LDS ----
#pragma unroll
    for (int m = 0; m < 4; m++)
#pragma unroll
      for (int kn = 0; kn < 2; kn++) {
        float zv = zl[kc*32 + kn*16 + rA];
#pragma unroll
        for (int r = 0; r < 4; r++) {
          float e = __expf(sacc[m][kn][r] * SCALE_) * zv;
          Pw[(m*16 + g*4 + r)*40 + kn*16 + rA] = f2b(e);
        }
      }
    // ---- oacc += P[64 x 32] @ v[32 x 64]  (K=32, single MFMA step) ----
    bf16x8 pa[4], vb[4];
#pragma unroll
    for (int m = 0; m < 4; m++)
      pa[m] = *(const bf16x8*)(Pw + (m*16 + rA)*40 + g*8);
#pragma unroll
    for (int n = 0; n < 4; n++) {
      int d = n*16 + rA;
      vb[n] = *(const bf16x8*)(vt + d*32 + ((g ^ ((d >> 1) & 3))*8));
    }
#pragma unroll
    for (int m = 0; m < 4; m++)
#pragma unroll
      for (int n = 0; n < 4; n++)
        oacc[m][n] = __builtin_amdgcn_mfma_f32_16x16x32_bf16(pa[m], vb[n], oacc[m][n], 0, 0, 0);
  }
  // ---- write attn (bf16, [B*N, 512] with col = h*64+d) ----
#pragma unroll
  for (int m = 0; m < 4; m++)
#pragma unroll
    for (int n = 0; n < 4; n++)
#pragma unroll
      for (int r = 0; r < 4; r++) {
        int q = qh*256 + w*64 + m*16 + g*4 + r;
        int dcol = h*64 + n*16 + rA;
        attn[(size_t)(b*512 + q)*512 + dcol] = f2b(oacc[m][n][r]);
      }
}

// ---------------- host launcher ----------------
extern "C" void kernel_launch(void* const* d_in, const int* in_sizes, int n_in,
                              void* d_out, int out_size, void* d_ws, size_t ws_size,
                              hipStream_t stream) {
  const float* Q  = (const float*)d_in[0];
  const float* K  = (const float*)d_in[1];
  const float* Wq = (const float*)d_in[2];
  const float* bq = (const float*)d_in[3];
  const float* Wk = (const float*)d_in[4];
  const float* bk = (const float*)d_in[5];
  const float* Wv = (const float*)d_in[6];
  const float* bv = (const float*)d_in[7];
  const float* Wo = (const float*)d_in[8];
  const float* bo = (const float*)d_in[9];
  const float* W1 = (const float*)d_in[10];
  const float* b1 = (const float*)d_in[11];
  const float* W2 = (const float*)d_in[12];
  const float* b2 = (const float*)d_in[13];
  float* out = (float*)d_out;

  const size_t SZ = (size_t)16384 * 512;        // 8388608 elems per [M,512] buffer
  ushort* Qb   = (ushort*)d_ws;                 // later reused as attn
  ushort* Kb   = Qb + SZ;                       // later reused as outb (post-O residual, bf16)
  ushort* qp   = Kb + SZ;                       // qp,kp,vp consecutive for fused qkv GEMM
  ushort* kp   = qp + SZ;
  ushort* vp   = kp + SZ;                       // later reused as h1
  ushort* vpT  = vp + SZ;
  ushort* Wb   = vpT + SZ;                      // 6 x 512x512 bf16 weights
  float*  zinv = (float*)(Wb + 6 * (size_t)262144);
  ushort* attn = Qb;
  ushort* outb = Kb;
  ushort* h1   = vp;

  // 1. convert Q, K, all weights to bf16
  k_cvt<<<dim3(17920), dim3(256), 0, stream>>>(Q, K, Wq, Wk, Wv, Wo, W1, W2, Qb, Kb, Wb);
  // 2. q/k/v projections (bias, bf16 out)
  k_gemm_qkv<<<dim3(128, 4, 3), dim3(256), 0, stream>>>(Qb, Kb, Wb, bq, bk, bv, qp);
  // 3. v -> vT per (b,h)
  k_tr<<<dim3(1024), dim3(256), 0, stream>>>(vp, vpT);
  // 4. column-softmax denominators
  k_z<<<dim3(512), dim3(256), 0, stream>>>(qp, kp, zinv);
  // 5. attention output (bf16)
  k_attn<<<dim3(512), dim3(256), 0, stream>>>(qp, kp, vpT, zinv, attn);
  // 6. out = Q + attn @ Wo^T + bo   (f32 to d_out, bf16 copy to outb)
  k_gemm<1><<<dim3(128, 4), dim3(256), 0, stream>>>(attn, Wb + 3*(size_t)262144, bo, Q, out, outb);
  // 7. h1 = relu(out @ W1^T + b1)
  k_gemm<2><<<dim3(128, 4), dim3(256), 0, stream>>>(outb, Wb + 4*(size_t)262144, b1, nullptr, nullptr, h1);
  // 8. d_out += h1 @ W2^T + b2
  k_gemm<3><<<dim3(128, 4), dim3(256), 0, stream>>>(h1, Wb + 5*(size_t)262144, b2, nullptr, out, nullptr);
}

// Round 2
// 193.942 us; speedup vs baseline: 1.0596x; 1.0596x over previous
//
#include <hip/hip_runtime.h>
#include <stdint.h>

// MAB block: B=32, N=512, D=512, H=8, dh=64.  M = B*N = 16384.
#define SCALE_ 0.044194173824159216f

typedef __attribute__((ext_vector_type(8))) short bf16x8;
typedef __attribute__((ext_vector_type(4))) float f32x4;

__device__ __forceinline__ ushort f2b(float f) {
  union { float f; uint32_t u; } v; v.f = f;
  return (ushort)((v.u + 0x7fffu + ((v.u >> 16) & 1u)) >> 16);  // RNE
}
__device__ __forceinline__ float b2f(ushort s) {
  union { uint32_t u; float f; } v; v.u = ((uint32_t)s) << 16; return v.f;
}
__device__ __forceinline__ uint32_t cvtpk(float lo, float hi) {
  uint32_t r; asm("v_cvt_pk_bf16_f32 %0, %1, %2" : "=v"(r) : "v"(lo), "v"(hi)); return r;
}
__device__ __forceinline__ void gld16(void* lds, const void* g) {
  __builtin_amdgcn_global_load_lds(
      (const __attribute__((address_space(1))) uint32_t*)g,
      (__attribute__((address_space(3))) uint32_t*)lds, 16, 0, 0);
}

// ---------------- fp32 -> bf16 convert (Q, K, 6 weights) ----------------
__global__ __launch_bounds__(256)
void k_cvt(const float* __restrict__ Q, const float* __restrict__ K,
           const float* __restrict__ w0, const float* __restrict__ w1,
           const float* __restrict__ w2, const float* __restrict__ w3,
           const float* __restrict__ w4, const float* __restrict__ w5,
           ushort* __restrict__ Qb, ushort* __restrict__ Kb, ushort* __restrict__ Wb)
{
  const long long NQ = 8388608LL, NW = 262144LL;
  long long i = ((long long)blockIdx.x * 256 + threadIdx.x) * 4;
  const float* src; ushort* dst; long long off;
  if (i < NQ)        { src = Q; dst = Qb; off = i; }
  else if (i < 2*NQ) { src = K; dst = Kb; off = i - NQ; }
  else {
    long long j = i - 2*NQ; int seg = (int)(j / NW); off = j - (long long)seg * NW;
    switch (seg) { case 0: src = w0; break; case 1: src = w1; break; case 2: src = w2; break;
                   case 3: src = w3; break; case 4: src = w4; break; default: src = w5; }
    dst = Wb + (size_t)seg * NW;
  }
  float4 v = *(const float4*)(src + off);
  ushort4 o = make_ushort4(f2b(v.x), f2b(v.y), f2b(v.z), f2b(v.w));
  *(ushort4*)(dst + off) = o;
}

// ---------------- GEMM C = A(bf16,[M,512]) @ Bw(bf16,[512,512])^T ----------------
// 128x128 tile, BK=32, 4 waves, global_load_lds w16, DOUBLE-BUFFERED 2-phase:
// stage(next) -> compute(cur) -> one barrier.  (T3 minimum recipe)
// EPI: 0 = bias->bf16  1 = Q + (acc+bias) -> f32 + bf16  2 = relu->bf16  3 = out += acc+bias
template<int EPI>
__device__ __forceinline__ void gemm_body(const ushort* __restrict__ A, const ushort* __restrict__ Bw,
                                          const float* __restrict__ bias, const float* __restrict__ extra,
                                          float* __restrict__ outf, ushort* __restrict__ outb,
                                          ushort* At, ushort* Bt, int m0, int n0)
{
  const int t = threadIdx.x;
  const int w = t >> 6, lane = t & 63;
  const int wr = w >> 1, wc = w & 1;
  const int rA = lane & 15, g = lane >> 4;
  const int c1 = w*64 + lane, c2 = c1 + 256;
  const ushort* gA1 = A  + (size_t)(m0 + (c1 >> 2))*512 + (c1 & 3)*8;
  const ushort* gA2 = A  + (size_t)(m0 + (c2 >> 2))*512 + (c2 & 3)*8;
  const ushort* gB1 = Bw + (size_t)(n0 + (c1 >> 2))*512 + (c1 & 3)*8;
  const ushort* gB2 = Bw + (size_t)(n0 + (c2 >> 2))*512 + (c2 & 3)*8;

#define G_STAGE(buf, kt) do { \
    gld16((char*)At + (buf)*8192 +        w*1024, gA1 + (kt)); \
    gld16((char*)At + (buf)*8192 + 4096 + w*1024, gA2 + (kt)); \
    gld16((char*)Bt + (buf)*8192 +        w*1024, gB1 + (kt)); \
    gld16((char*)Bt + (buf)*8192 + 4096 + w*1024, gB2 + (kt)); } while (0)

  G_STAGE(0, 0);
  __syncthreads();
  f32x4 acc[4][4] = {};
  for (int kt = 0; kt < 16; kt++) {
    const int cur = kt & 1;
    if (kt < 15) G_STAGE(cur ^ 1, (kt + 1)*32);
    const ushort* Ab = At + cur*4096;
    const ushort* Bb = Bt + cur*4096;
    bf16x8 af[4], bfr[4];
#pragma unroll
    for (int m = 0; m < 4; m++) af[m]  = *(const bf16x8*)(Ab + (wr*64 + m*16 + rA)*32 + g*8);
#pragma unroll
    for (int n = 0; n < 4; n++) bfr[n] = *(const bf16x8*)(Bb + (wc*64 + n*16 + rA)*32 + g*8);
#pragma unroll
    for (int m = 0; m < 4; m++)
#pragma unroll
      for (int n = 0; n < 4; n++)
        acc[m][n] = __builtin_amdgcn_mfma_f32_16x16x32_bf16(af[m], bfr[n], acc[m][n], 0, 0, 0);
    __syncthreads();     // drains stage(next); all waves done reading cur
  }
#undef G_STAGE
#pragma unroll
  for (int m = 0; m < 4; m++)
#pragma unroll
    for (int n = 0; n < 4; n++) {
      int col = n0 + wc*64 + n*16 + rA;
      float bb = bias[col];
#pragma unroll
      for (int r = 0; r < 4; r++) {
        int row = m0 + wr*64 + m*16 + g*4 + r;
        size_t idx = (size_t)row*512 + col;
        float v = acc[m][n][r] + bb;
        if (EPI == 0)      outb[idx] = f2b(v);
        else if (EPI == 1) { float o = extra[idx] + v; outf[idx] = o; outb[idx] = f2b(o); }
        else if (EPI == 2) outb[idx] = f2b(v > 0.f ? v : 0.f);
        else               outf[idx] += v;
      }
    }
}

template<int EPI>
__global__ __launch_bounds__(256)
void k_gemm(const ushort* __restrict__ A, const ushort* __restrict__ Bw,
            const float* __restrict__ bias, const float* __restrict__ extra,
            float* __restrict__ outf, ushort* __restrict__ outb)
{
  __shared__ __align__(16) ushort At[2*4096], Bt[2*4096];
  gemm_body<EPI>(A, Bw, bias, extra, outf, outb, At, Bt, blockIdx.x*128, blockIdx.y*128);
}

__global__ __launch_bounds__(256)
void k_gemm_qkv(const ushort* __restrict__ Qb, const ushort* __restrict__ Kb,
                const ushort* __restrict__ Wb, const float* __restrict__ bq,
                const float* __restrict__ bk, const float* __restrict__ bvv,
                ushort* __restrict__ out)
{
  __shared__ __align__(16) ushort At[2*4096], Bt[2*4096];
  int z = blockIdx.z;
  const ushort* A = (z == 0) ? Qb : Kb;
  const float* bias = (z == 0) ? bq : ((z == 1) ? bk : bvv);
  gemm_body<0>(A, Wb + (size_t)z*262144, bias, nullptr, nullptr,
               out + (size_t)z*8388608, At, Bt, blockIdx.x*128, blockIdx.y*128);
}

// ---------------- K2: zinv[bh,k] = 1/sum_q exp(s*scale) ----------------
// block = (b,h,khalf); wave owns 64 k-cols. K-fragments register-resident;
// qt (64q x 64d) double-buffered in LDS, 2-phase staging.
__global__ __launch_bounds__(256)
void k_z(const ushort* __restrict__ qp, const ushort* __restrict__ kp, float* __restrict__ zinv)
{
  __shared__ __align__(16) ushort qt[2*4096];   // 2 x [64 q][64 d], 16KB
  int bid = blockIdx.x;
  int bh = bid >> 1, kh = bid & 1;
  int b = bh >> 3, h = bh & 7;
  int t = threadIdx.x, w = t >> 6, lane = t & 63;
  int rA = lane & 15, g = lane >> 4;
  const ushort* qbase = qp + (size_t)(b*512)*512 + h*64;
  // K fragments in registers: wave's 64 k-cols x 64 d  (B-frag: lane holds col k=rA, d=g*8..+7)
  bf16x8 kf[4][2];
#pragma unroll
  for (int n = 0; n < 4; n++)
#pragma unroll
    for (int ks = 0; ks < 2; ks++)
      kf[n][ks] = *(const bf16x8*)(kp + (size_t)(b*512 + kh*256 + w*64 + n*16 + rA)*512 + h*64 + ks*32 + g*8);

#define Z_STAGE(buf, qb) do { \
    _Pragma("unroll") \
    for (int i = 0; i < 2; i++) { \
      int c = (w*2 + i)*64 + lane; \
      int row = c >> 3, sl = c & 7; \
      gld16((char*)qt + (buf)*8192 + (w*2 + i)*1024, \
            qbase + (size_t)((qb)*64 + row)*512 + ((sl ^ (row & 7))*8)); } } while (0)

  Z_STAGE(0, 0);
  __syncthreads();
  float Zacc[4] = {0.f, 0.f, 0.f, 0.f};
  for (int qb = 0; qb < 8; qb++) {
    const int cur = qb & 1;
    if (qb < 7) Z_STAGE(cur ^ 1, qb + 1);
    const ushort* qtb = qt + cur*4096;
    f32x4 acc[4][4] = {};
#pragma unroll
    for (int ks = 0; ks < 2; ks++) {
      bf16x8 af[4];
#pragma unroll
      for (int m = 0; m < 4; m++) {
        int q = m*16 + rA;
        af[m] = *(const bf16x8*)(qtb + q*64 + (((ks*4 + g) ^ (q & 7))*8));
      }
#pragma unroll
      for (int m = 0; m < 4; m++)
#pragma unroll
        for (int n = 0; n < 4; n++)
          acc[m][n] = __builtin_amdgcn_mfma_f32_16x16x32_bf16(af[m], kf[n][ks], acc[m][n], 0, 0, 0);
    }
#pragma unroll
    for (int m = 0; m < 4; m++)
#pragma unroll
      for (int n = 0; n < 4; n++) {
        float s = 0.f;
#pragma unroll
        for (int r = 0; r < 4; r++) s += __expf(acc[m][n][r] * SCALE_);
        Zacc[n] += s;
      }
    __syncthreads();
  }
#undef Z_STAGE
#pragma unroll
  for (int n = 0; n < 4; n++) {
    float v = Zacc[n];
    v += __shfl_xor(v, 16);
    v += __shfl_xor(v, 32);
    if (lane < 16) zinv[(size_t)bh*512 + kh*256 + w*64 + n*16 + lane] = 1.0f / v;
  }
}

// ---------------- transpose + zinv fold: vpT[(b,h,d), k] = vp[b,k,h*64+d] * zinv[bh,k] ----------------
__global__ __launch_bounds__(256)
void k_tr(const ushort* __restrict__ vp, const float* __restrict__ zinv, ushort* __restrict__ vpT)
{
  __shared__ __align__(16) ushort tile[128][72];
  int bid = blockIdx.x;                   // bh*4 + kb
  int bh = bid >> 2, kb = bid & 3;
  int b = bh >> 3, h = bh & 7;
  int t = threadIdx.x;
#pragma unroll
  for (int i = 0; i < 4; i++) {           // load [128 k][64 d], scale by zinv[k]
    int c = i*256 + t; int row = c >> 3, cg = c & 7;
    union { ushort s[8]; bf16x8 v; } u;
    u.v = *(const bf16x8*)(vp + (size_t)(b*512 + kb*128 + row)*512 + h*64 + cg*8);
    float zv = zinv[(size_t)bh*512 + kb*128 + row];
#pragma unroll
    for (int j = 0; j < 8; j++) u.s[j] = f2b(b2f(u.s[j]) * zv);
    *(bf16x8*)&tile[row][cg*8] = u.v;
  }
  __syncthreads();
#pragma unroll
  for (int i = 0; i < 4; i++) {           // store [64 d][128 k]
    int c = i*256 + t; int d = c >> 4, kg = c & 15;
    union { ushort s[8]; bf16x8 v; } tmp;
#pragma unroll
    for (int j = 0; j < 8; j++) tmp.s[j] = tile[kg*8 + j][d];
    *(bf16x8*)(vpT + (size_t)(bh*64 + d)*512 + kb*128 + kg*8) = tmp.v;
  }
}

// ---------------- K3: attn = exp(QK^T*scale) @ V'   (V' has zinv folded in) ----------------
// block = (b,h,qhalf); wave owns 64 q x 64 d.  Swapped QK^T (mfma(K,Q)) so each lane
// holds 4 consecutive k per q-row -> packed b64 P-writes.  Q-fragments in registers.
__global__ __launch_bounds__(256)
void k_attn(const ushort* __restrict__ qp, const ushort* __restrict__ kp,
            const ushort* __restrict__ vpT, ushort* __restrict__ attn)
{
  __shared__ __align__(16) ushort kt2[2*2048];  // 2 x [32 k][64 d], 8KB (slot ^ (k&7) swizzle)
  __shared__ __align__(16) ushort vt2[2*2048];  // 2 x [64 d][32 k], 8KB (slot ^ (d&3) swizzle)
  __shared__ __align__(16) ushort P[4][2048];   // per-wave [64 q][32 k], 16KB (slot ^ (q&3))
  int bid = blockIdx.x;
  int bh = bid >> 1, qh = bid & 1;
  int b = bh >> 3, h = bh & 7;
  int t = threadIdx.x, w = t >> 6, lane = t & 63;
  int rA = lane & 15, g = lane >> 4;
  const ushort* kbase = kp + (size_t)(b*512)*512 + h*64;
  const ushort* vbase = vpT + (size_t)bh*64*512;
  ushort* Pw = &P[w][0];
  // Q fragments in registers (B-frag of swapped QK: lane holds col q = m*16+rA, d = ks*32+g*8..+7)
  bf16x8 qf[4][2];
#pragma unroll
  for (int m = 0; m < 4; m++)
#pragma unroll
    for (int ks = 0; ks < 2; ks++)
      qf[m][ks] = *(const bf16x8*)(qp + (size_t)(b*512 + qh*256 + w*64 + m*16 + rA)*512 + h*64 + ks*32 + g*8);

#define A_STAGE(buf, kc) do { \
    int c = w*64 + lane; \
    { int k = c >> 3, sl = c & 7; \
      gld16((char*)kt2 + (buf)*4096 + w*1024, \
            kbase + (size_t)((kc)*32 + k)*512 + ((sl ^ (k & 7))*8)); } \
    { int d = c >> 2, sl = c & 3; \
      gld16((char*)vt2 + (buf)*4096 + w*1024, \
            vbase + (size_t)d*512 + (kc)*32 + ((sl ^ (d & 3))*8)); } } while (0)

  A_STAGE(0, 0);
  __syncthreads();
  f32x4 oacc[4][4] = {};
  for (int kc = 0; kc < 16; kc++) {
    const int cur = kc & 1;
    if (kc < 15) A_STAGE(cur ^ 1, kc + 1);
    const ushort* ktb = kt2 + cur*2048;
    const ushort* vtb = vt2 + cur*2048;
    // ---- QK^T swapped: D[k,q]; A=K (rows k), B=Q (cols q) ----
    bf16x8 kf[2][2];
#pragma unroll
    for (int kn = 0; kn < 2; kn++)
#pragma unroll
      for (int ks = 0; ks < 2; ks++) {
        int k = kn*16 + rA;
        kf[kn][ks] = *(const bf16x8*)(ktb + k*64 + (((ks*4 + g) ^ (k & 7))*8));
      }
    f32x4 sacc[2][4] = {};
    __builtin_amdgcn_s_setprio(1);
#pragma unroll
    for (int ks = 0; ks < 2; ks++)
#pragma unroll
      for (int kn = 0; kn < 2; kn++)
#pragma unroll
        for (int m = 0; m < 4; m++)
          sacc[kn][m] = __builtin_amdgcn_mfma_f32_16x16x32_bf16(kf[kn][ks], qf[m][ks], sacc[kn][m], 0, 0, 0);
    __builtin_amdgcn_s_setprio(0);
    // ---- P[q][k] = exp(s*scale), packed b64 writes (lane: q=m*16+rA, k=kn*16+g*4..+3) ----
#pragma unroll
    for (int m = 0; m < 4; m++)
#pragma unroll
      for (int kn = 0; kn < 2; kn++) {
        float e0 = __expf(sacc[kn][m][0] * SCALE_);
        float e1 = __expf(sacc[kn][m][1] * SCALE_);
        float e2 = __expf(sacc[kn][m][2] * SCALE_);
        float e3 = __expf(sacc[kn][m][3] * SCALE_);
        uint2 pk; pk.x = cvtpk(e0, e1); pk.y = cvtpk(e2, e3);
        int q = m*16 + rA;
        int kb2 = kn*32 + g*8;                       // byte offset of k within row
        *(uint2*)((char*)Pw + q*64 + (kb2 ^ ((q & 3) << 4))) = pk;
      }
    // ---- PV: oacc += P[64q x 32k] @ V'[32k x 64d] ----
    bf16x8 pa[4], vb[4];
#pragma unroll
    for (int m = 0; m < 4; m++) {
      int q = m*16 + rA;
      pa[m] = *(const bf16x8*)((const char*)Pw + q*64 + ((g*16) ^ ((q & 3) << 4)));
    }
#pragma unroll
    for (int n = 0; n < 4; n++) {
      int d = n*16 + rA;
      vb[n] = *(const bf16x8*)((const char*)vtb + d*64 + ((g*16) ^ ((d & 3) << 4)));
    }
    __builtin_amdgcn_s_setprio(1);
#pragma unroll
    for (int m = 0; m < 4; m++)
#pragma unroll
      for (int n = 0; n < 4; n++)
        oacc[m][n] = __builtin_amdgcn_mfma_f32_16x16x32_bf16(pa[m], vb[n], oacc[m][n], 0, 0, 0);
    __builtin_amdgcn_s_setprio(0);
    __syncthreads();   // drains stage(next); all waves done with cur bufs
  }
#undef A_STAGE
#pragma unroll
  for (int m = 0; m < 4; m++)
#pragma unroll
    for (int n = 0; n < 4; n++)
#pragma unroll
      for (int r = 0; r < 4; r++) {
        int q = qh*256 + w*64 + m*16 + g*4 + r;
        int dcol = h*64 + n*16 + rA;
        attn[(size_t)(b*512 + q)*512 + dcol] = f2b(oacc[m][n][r]);
      }
}

// ---------------- host launcher ----------------
extern "C" void kernel_launch(void* const* d_in, const int* in_sizes, int n_in,
                              void* d_out, int out_size, void* d_ws, size_t ws_size,
                              hipStream_t stream) {
  const float* Q  = (const float*)d_in[0];
  const float* K  = (const float*)d_in[1];
  const float* Wq = (const float*)d_in[2];
  const float* bq = (const float*)d_in[3];
  const float* Wk = (const float*)d_in[4];
  const float* bk = (const float*)d_in[5];
  const float* Wv = (const float*)d_in[6];
  const float* bv = (const float*)d_in[7];
  const float* Wo = (const float*)d_in[8];
  const float* bo = (const float*)d_in[9];
  const float* W1 = (const float*)d_in[10];
  const float* b1 = (const float*)d_in[11];
  const float* W2 = (const float*)d_in[12];
  const float* b2 = (const float*)d_in[13];
  float* out = (float*)d_out;

  const size_t SZ = (size_t)16384 * 512;
  ushort* Qb   = (ushort*)d_ws;                 // later reused as attn
  ushort* Kb   = Qb + SZ;                       // later reused as outb
  ushort* qp   = Kb + SZ;
  ushort* kp   = qp + SZ;
  ushort* vp   = kp + SZ;                       // later reused as h1
  ushort* vpT  = vp + SZ;                       // zinv-folded V'
  ushort* Wb   = vpT + SZ;
  float*  zinv = (float*)(Wb + 6 * (size_t)262144);
  ushort* attn = Qb;
  ushort* outb = Kb;
  ushort* h1   = vp;

  k_cvt<<<dim3(17920), dim3(256), 0, stream>>>(Q, K, Wq, Wk, Wv, Wo, W1, W2, Qb, Kb, Wb);
  k_gemm_qkv<<<dim3(128, 4, 3), dim3(256), 0, stream>>>(Qb, Kb, Wb, bq, bk, bv, qp);
  k_z<<<dim3(512), dim3(256), 0, stream>>>(qp, kp, zinv);
  k_tr<<<dim3(1024), dim3(256), 0, stream>>>(vp, zinv, vpT);
  k_attn<<<dim3(512), dim3(256), 0, stream>>>(qp, kp, vpT, attn);
  k_gemm<1><<<dim3(128, 4), dim3(256), 0, stream>>>(attn, Wb + 3*(size_t)262144, bo, Q, out, outb);
  k_gemm<2><<<dim3(128, 4), dim3(256), 0, stream>>>(outb, Wb + 4*(size_t)262144, b1, nullptr, nullptr, h1);
  k_gemm<3><<<dim3(128, 4), dim3(256), 0, stream>>>(h1, Wb + 5*(size_t)262144, b2, nullptr, out, nullptr);
}

// Round 3
// 180.941 us; speedup vs baseline: 1.1358x; 1.0719x over previous
//
#include <hip/hip_runtime.h>
#include <stdint.h>

// MAB block: B=32, N=512, D=512, H=8, dh=64.  M = B*N = 16384.
#define SCALE_ 0.044194173824159216f

typedef __attribute__((ext_vector_type(8))) short bf16x8;
typedef __attribute__((ext_vector_type(4))) float f32x4;

__device__ __forceinline__ ushort f2b(float f) {
  union { float f; uint32_t u; } v; v.f = f;
  return (ushort)((v.u + 0x7fffu + ((v.u >> 16) & 1u)) >> 16);  // RNE
}
__device__ __forceinline__ uint32_t cvtpk(float lo, float hi) {
  uint32_t r; asm("v_cvt_pk_bf16_f32 %0, %1, %2" : "=v"(r) : "v"(lo), "v"(hi)); return r;
}
__device__ __forceinline__ void gld16(void* lds, const void* g) {
  __builtin_amdgcn_global_load_lds(
      (const __attribute__((address_space(1))) uint32_t*)g,
      (__attribute__((address_space(3))) uint32_t*)lds, 16, 0, 0);
}

// ---------------- fp32 -> bf16 convert (Q, K, 6 weights) ----------------
__global__ __launch_bounds__(256)
void k_cvt(const float* __restrict__ Q, const float* __restrict__ K,
           const float* __restrict__ w0, const float* __restrict__ w1,
           const float* __restrict__ w2, const float* __restrict__ w3,
           const float* __restrict__ w4, const float* __restrict__ w5,
           ushort* __restrict__ Qb, ushort* __restrict__ Kb, ushort* __restrict__ Wb)
{
  const long long NQ = 8388608LL, NW = 262144LL;
  long long i = ((long long)blockIdx.x * 256 + threadIdx.x) * 4;
  const float* src; ushort* dst; long long off;
  if (i < NQ)        { src = Q; dst = Qb; off = i; }
  else if (i < 2*NQ) { src = K; dst = Kb; off = i - NQ; }
  else {
    long long j = i - 2*NQ; int seg = (int)(j / NW); off = j - (long long)seg * NW;
    switch (seg) { case 0: src = w0; break; case 1: src = w1; break; case 2: src = w2; break;
                   case 3: src = w3; break; case 4: src = w4; break; default: src = w5; }
    dst = Wb + (size_t)seg * NW;
  }
  float4 v = *(const float4*)(src + off);
  ushort4 o = make_ushort4(f2b(v.x), f2b(v.y), f2b(v.z), f2b(v.w));
  *(ushort4*)(dst + off) = o;
}

// ---------------- GEMM C = A(bf16,[M,512]) @ Bw(bf16,[512,512])^T ----------------
// 128x128 tile, BK=32, 4 waves, global_load_lds w16, double-buffered 2-phase.
// EPI: 0 = bias->bf16  1 = Q + (acc+bias) -> f32 + bf16  2 = relu->bf16
//      3 = out += acc+bias  4 = v-projection: write transposed vpT[(b,h,d),k] (bias added)
template<int EPI>
__device__ __forceinline__ void gemm_body(const ushort* __restrict__ A, const ushort* __restrict__ Bw,
                                          const float* __restrict__ bias, const float* __restrict__ extra,
                                          float* __restrict__ outf, ushort* __restrict__ outb,
                                          ushort* At, ushort* Bt, int m0, int n0)
{
  const int t = threadIdx.x;
  const int w = t >> 6, lane = t & 63;
  const int wr = w >> 1, wc = w & 1;
  const int rA = lane & 15, g = lane >> 4;
  const int c1 = w*64 + lane, c2 = c1 + 256;
  const ushort* gA1 = A  + (size_t)(m0 + (c1 >> 2))*512 + (c1 & 3)*8;
  const ushort* gA2 = A  + (size_t)(m0 + (c2 >> 2))*512 + (c2 & 3)*8;
  const ushort* gB1 = Bw + (size_t)(n0 + (c1 >> 2))*512 + (c1 & 3)*8;
  const ushort* gB2 = Bw + (size_t)(n0 + (c2 >> 2))*512 + (c2 & 3)*8;

#define G_STAGE(buf, kt) do { \
    gld16((char*)At + (buf)*8192 +        w*1024, gA1 + (kt)); \
    gld16((char*)At + (buf)*8192 + 4096 + w*1024, gA2 + (kt)); \
    gld16((char*)Bt + (buf)*8192 +        w*1024, gB1 + (kt)); \
    gld16((char*)Bt + (buf)*8192 + 4096 + w*1024, gB2 + (kt)); } while (0)

  G_STAGE(0, 0);
  __syncthreads();
  f32x4 acc[4][4] = {};
  for (int kt = 0; kt < 16; kt++) {
    const int cur = kt & 1;
    if (kt < 15) G_STAGE(cur ^ 1, (kt + 1)*32);
    const ushort* Ab = At + cur*4096;
    const ushort* Bb = Bt + cur*4096;
    bf16x8 af[4], bfr[4];
#pragma unroll
    for (int m = 0; m < 4; m++) af[m]  = *(const bf16x8*)(Ab + (wr*64 + m*16 + rA)*32 + g*8);
#pragma unroll
    for (int n = 0; n < 4; n++) bfr[n] = *(const bf16x8*)(Bb + (wc*64 + n*16 + rA)*32 + g*8);
    __builtin_amdgcn_s_setprio(1);
#pragma unroll
    for (int m = 0; m < 4; m++)
#pragma unroll
      for (int n = 0; n < 4; n++)
        acc[m][n] = __builtin_amdgcn_mfma_f32_16x16x32_bf16(af[m], bfr[n], acc[m][n], 0, 0, 0);
    __builtin_amdgcn_s_setprio(0);
    __syncthreads();     // drains stage(next); all waves done reading cur
  }
#undef G_STAGE
#pragma unroll
  for (int m = 0; m < 4; m++)
#pragma unroll
    for (int n = 0; n < 4; n++) {
      int col = n0 + wc*64 + n*16 + rA;
      float bb = bias[col];
      if (EPI == 4) {
        // transposed write: C[row=k, col=h*64+d] -> vpT[(b*8+h)*64+d][k], 4 k packed per store
        int b = m0 >> 9, k0 = m0 & 511;
        int hh = col >> 6, dl = col & 63;
        int kg = k0 + wr*64 + m*16 + g*4;
        float v0 = acc[m][n][0] + bb, v1 = acc[m][n][1] + bb;
        float v2 = acc[m][n][2] + bb, v3 = acc[m][n][3] + bb;
        uint2 pk;
        pk.x = (uint32_t)f2b(v0) | ((uint32_t)f2b(v1) << 16);
        pk.y = (uint32_t)f2b(v2) | ((uint32_t)f2b(v3) << 16);
        *(uint2*)(outb + ((size_t)((b*8 + hh)*64 + dl)*512 + kg)) = pk;
      } else {
#pragma unroll
        for (int r = 0; r < 4; r++) {
          int row = m0 + wr*64 + m*16 + g*4 + r;
          size_t idx = (size_t)row*512 + col;
          float v = acc[m][n][r] + bb;
          if (EPI == 0)      outb[idx] = f2b(v);
          else if (EPI == 1) { float o = extra[idx] + v; outf[idx] = o; outb[idx] = f2b(o); }
          else if (EPI == 2) outb[idx] = f2b(v > 0.f ? v : 0.f);
          else               outf[idx] += v;
        }
      }
    }
}

template<int EPI>
__global__ __launch_bounds__(256)
void k_gemm(const ushort* __restrict__ A, const ushort* __restrict__ Bw,
            const float* __restrict__ bias, const float* __restrict__ extra,
            float* __restrict__ outf, ushort* __restrict__ outb)
{
  __shared__ __align__(16) ushort At[2*4096], Bt[2*4096];
  gemm_body<EPI>(A, Bw, bias, extra, outf, outb, At, Bt, blockIdx.x*128, blockIdx.y*128);
}

// fused qkv projection; z=2 (v) writes transposed vpT directly
__global__ __launch_bounds__(256)
void k_gemm_qkv(const ushort* __restrict__ Qb, const ushort* __restrict__ Kb,
                const ushort* __restrict__ Wb, const float* __restrict__ bq,
                const float* __restrict__ bk, const float* __restrict__ bvv,
                ushort* __restrict__ qkout, ushort* __restrict__ vpT)
{
  __shared__ __align__(16) ushort At[2*4096], Bt[2*4096];
  int z = blockIdx.z;
  if (z == 2) {
    gemm_body<4>(Kb, Wb + 2*(size_t)262144, bvv, nullptr, nullptr,
                 vpT, At, Bt, blockIdx.x*128, blockIdx.y*128);
  } else {
    const ushort* A = (z == 0) ? Qb : Kb;
    const float* bias = (z == 0) ? bq : bk;
    gemm_body<0>(A, Wb + (size_t)z*262144, bias, nullptr, nullptr,
                 qkout + (size_t)z*8388608, At, Bt, blockIdx.x*128, blockIdx.y*128);
  }
}

// ---------------- K2: zinv[bh,k] = 1/sum_q exp(s*scale) ----------------
// block = (b,h,khalf); wave owns 64 k-cols (K-frags in registers).
// q processed in blocks of 128 rows, double-buffered qt, 64 MFMA per barrier.
__global__ __launch_bounds__(256, 2)
void k_z(const ushort* __restrict__ qp, const ushort* __restrict__ kp, float* __restrict__ zinv)
{
  __shared__ __align__(16) ushort qt[2*8192];   // 2 x [128 q][64 d] (swizzled), 32KB
  int bid = blockIdx.x;
  int bh = bid >> 1, kh = bid & 1;
  int b = bh >> 3, h = bh & 7;
  int t = threadIdx.x, w = t >> 6, lane = t & 63;
  int rA = lane & 15, g = lane >> 4;
  const ushort* qbase = qp + (size_t)(b*512)*512 + h*64;
  bf16x8 kf[4][2];
#pragma unroll
  for (int n = 0; n < 4; n++)
#pragma unroll
    for (int ks = 0; ks < 2; ks++)
      kf[n][ks] = *(const bf16x8*)(kp + (size_t)(b*512 + kh*256 + w*64 + n*16 + rA)*512 + h*64 + ks*32 + g*8);

#define Z_STAGE(buf, qb) do { \
    _Pragma("unroll") \
    for (int i = 0; i < 4; i++) { \
      int c = i*256 + w*64 + lane; \
      int row = c >> 3, sl = c & 7; \
      gld16((char*)qt + (buf)*16384 + i*4096 + w*1024, \
            qbase + (size_t)((qb)*128 + row)*512 + ((sl ^ (row & 7))*8)); } } while (0)

  Z_STAGE(0, 0);
  __syncthreads();
  float Zacc[4] = {0.f, 0.f, 0.f, 0.f};
  for (int qb = 0; qb < 4; qb++) {
    const int cur = qb & 1;
    if (qb < 3) Z_STAGE(cur ^ 1, qb + 1);
    const ushort* qtb = qt + cur*8192;
    f32x4 acc[8][4] = {};
#pragma unroll
    for (int ks = 0; ks < 2; ks++) {
      bf16x8 af[8];
#pragma unroll
      for (int m = 0; m < 8; m++) {
        int q = m*16 + rA;
        af[m] = *(const bf16x8*)(qtb + q*64 + (((ks*4 + g) ^ (q & 7))*8));
      }
      __builtin_amdgcn_s_setprio(1);
#pragma unroll
      for (int m = 0; m < 8; m++)
#pragma unroll
        for (int n = 0; n < 4; n++)
          acc[m][n] = __builtin_amdgcn_mfma_f32_16x16x32_bf16(af[m], kf[n][ks], acc[m][n], 0, 0, 0);
      __builtin_amdgcn_s_setprio(0);
    }
#pragma unroll
    for (int m = 0; m < 8; m++)
#pragma unroll
      for (int n = 0; n < 4; n++) {
        float s = 0.f;
#pragma unroll
        for (int r = 0; r < 4; r++) s += __expf(acc[m][n][r] * SCALE_);
        Zacc[n] += s;
      }
    __syncthreads();
  }
#undef Z_STAGE
#pragma unroll
  for (int n = 0; n < 4; n++) {
    float v = Zacc[n];
    v += __shfl_xor(v, 16);
    v += __shfl_xor(v, 32);
    if (lane < 16) zinv[(size_t)bh*512 + kh*256 + w*64 + n*16 + lane] = 1.0f / v;
  }
}

// ---------------- K3: attn = (exp(QK^T*scale)*zinv) @ V ----------------
// block = (b,h,qhalf); wave owns 64 q x 64 d.  k chunks of 64; swapped QK^T;
// Q-frags in registers; zinv applied to P in f32 before bf16 pack.
__global__ __launch_bounds__(256, 2)
void k_attn(const ushort* __restrict__ qp, const ushort* __restrict__ kp,
            const ushort* __restrict__ vpT, const float* __restrict__ zinv,
            ushort* __restrict__ attn)
{
  __shared__ __align__(16) ushort kt2[2*4096];  // 2 x [64 k][64 d] swizzled, 16KB
  __shared__ __align__(16) ushort vt2[2*4096];  // 2 x [64 d][64 k] swizzled, 16KB
  __shared__ __align__(16) ushort P[4*4096];    // per-wave [64 q][64 k] swizzled, 32KB
  __shared__ float zl[512];
  int bid = blockIdx.x;
  int bh = bid >> 1, qh = bid & 1;
  int b = bh >> 3, h = bh & 7;
  int t = threadIdx.x, w = t >> 6, lane = t & 63;
  int rA = lane & 15, g = lane >> 4;
  const ushort* kbase = kp + (size_t)(b*512)*512 + h*64;
  const ushort* vbase = vpT + (size_t)bh*64*512;
  ushort* Pw = P + w*4096;
  bf16x8 qf[4][2];
#pragma unroll
  for (int m = 0; m < 4; m++)
#pragma unroll
    for (int ks = 0; ks < 2; ks++)
      qf[m][ks] = *(const bf16x8*)(qp + (size_t)(b*512 + qh*256 + w*64 + m*16 + rA)*512 + h*64 + ks*32 + g*8);

#define A_STAGE(buf, kc) do { \
    _Pragma("unroll") \
    for (int i = 0; i < 2; i++) { \
      int c = i*256 + w*64 + lane; \
      { int k = c >> 3, sl = c & 7; \
        gld16((char*)kt2 + (buf)*8192 + i*4096 + w*1024, \
              kbase + (size_t)((kc)*64 + k)*512 + ((sl ^ (k & 7))*8)); } \
      { int d = c >> 3, sl = c & 7; \
        gld16((char*)vt2 + (buf)*8192 + i*4096 + w*1024, \
              vbase + (size_t)d*512 + (kc)*64 + ((sl ^ (d & 7))*8)); } } } while (0)

  A_STAGE(0, 0);
  zl[t]       = zinv[(size_t)bh*512 + t];
  zl[t + 256] = zinv[(size_t)bh*512 + t + 256];
  __syncthreads();
  f32x4 oacc[4][4] = {};
  for (int kc = 0; kc < 8; kc++) {
    const int cur = kc & 1;
    if (kc < 7) A_STAGE(cur ^ 1, kc + 1);
    const ushort* ktb = kt2 + cur*4096;
    const ushort* vtb = vt2 + cur*4096;
    // ---- QK^T swapped (D[k,q]) in two kn-halves to cap VGPR ----
#pragma unroll
    for (int knh = 0; knh < 2; knh++) {
      f32x4 sacc[2][4] = {};
#pragma unroll
      for (int ks = 0; ks < 2; ks++) {
        bf16x8 kfr[2];
#pragma unroll
        for (int kn2 = 0; kn2 < 2; kn2++) {
          int k = (knh*2 + kn2)*16 + rA;
          kfr[kn2] = *(const bf16x8*)(ktb + k*64 + (((ks*4 + g) ^ (k & 7))*8));
        }
        __builtin_amdgcn_s_setprio(1);
#pragma unroll
        for (int kn2 = 0; kn2 < 2; kn2++)
#pragma unroll
          for (int m = 0; m < 4; m++)
            sacc[kn2][m] = __builtin_amdgcn_mfma_f32_16x16x32_bf16(kfr[kn2], qf[m][ks], sacc[kn2][m], 0, 0, 0);
        __builtin_amdgcn_s_setprio(0);
      }
      // ---- P[q][k] = exp(s*scale)*zinv[k], packed b64 swizzled writes ----
#pragma unroll
      for (int kn2 = 0; kn2 < 2; kn2++) {
        int kn = knh*2 + kn2;
        f32x4 zv = *(const f32x4*)&zl[kc*64 + kn*16 + g*4];
#pragma unroll
        for (int m = 0; m < 4; m++) {
          float e0 = __expf(sacc[kn2][m][0] * SCALE_) * zv[0];
          float e1 = __expf(sacc[kn2][m][1] * SCALE_) * zv[1];
          float e2 = __expf(sacc[kn2][m][2] * SCALE_) * zv[2];
          float e3 = __expf(sacc[kn2][m][3] * SCALE_) * zv[3];
          uint2 pk; pk.x = cvtpk(e0, e1); pk.y = cvtpk(e2, e3);
          int q = m*16 + rA;
          int kb2 = kn*32 + g*8;
          *(uint2*)((char*)Pw + q*128 + (kb2 ^ ((q & 7) << 4))) = pk;
        }
      }
    }
    // ---- PV: oacc += P[64q x 64k] @ V[64k x 64d] ----
#pragma unroll
    for (int ks = 0; ks < 2; ks++) {
      bf16x8 pa[4], vb[4];
#pragma unroll
      for (int m = 0; m < 4; m++) {
        int q = m*16 + rA;
        pa[m] = *(const bf16x8*)((const char*)Pw + q*128 + ((ks*64 + g*16) ^ ((q & 7) << 4)));
      }
#pragma unroll
      for (int n = 0; n < 4; n++) {
        int d = n*16 + rA;
        vb[n] = *(const bf16x8*)((const char*)vtb + d*128 + ((ks*64 + g*16) ^ ((d & 7) << 4)));
      }
      __builtin_amdgcn_s_setprio(1);
#pragma unroll
      for (int m = 0; m < 4; m++)
#pragma unroll
        for (int n = 0; n < 4; n++)
          oacc[m][n] = __builtin_amdgcn_mfma_f32_16x16x32_bf16(pa[m], vb[n], oacc[m][n], 0, 0, 0);
      __builtin_amdgcn_s_setprio(0);
    }
    __syncthreads();   // drains stage(next); all waves done with cur bufs
  }
#undef A_STAGE
#pragma unroll
  for (int m = 0; m < 4; m++)
#pragma unroll
    for (int n = 0; n < 4; n++)
#pragma unroll
      for (int r = 0; r < 4; r++) {
        int q = qh*256 + w*64 + m*16 + g*4 + r;
        int dcol = h*64 + n*16 + rA;
        attn[(size_t)(b*512 + q)*512 + dcol] = f2b(oacc[m][n][r]);
      }
}

// ---------------- host launcher ----------------
extern "C" void kernel_launch(void* const* d_in, const int* in_sizes, int n_in,
                              void* d_out, int out_size, void* d_ws, size_t ws_size,
                              hipStream_t stream) {
  const float* Q  = (const float*)d_in[0];
  const float* K  = (const float*)d_in[1];
  const float* Wq = (const float*)d_in[2];
  const float* bq = (const float*)d_in[3];
  const float* Wk = (const float*)d_in[4];
  const float* bk = (const float*)d_in[5];
  const float* Wv = (const float*)d_in[6];
  const float* bv = (const float*)d_in[7];
  const float* Wo = (const float*)d_in[8];
  const float* bo = (const float*)d_in[9];
  const float* W1 = (const float*)d_in[10];
  const float* b1 = (const float*)d_in[11];
  const float* W2 = (const float*)d_in[12];
  const float* b2 = (const float*)d_in[13];
  float* out = (float*)d_out;

  const size_t SZ = (size_t)16384 * 512;
  ushort* Qb   = (ushort*)d_ws;                 // later reused as attn
  ushort* Kb   = Qb + SZ;                       // later reused as outb
  ushort* qp   = Kb + SZ;
  ushort* kp   = qp + SZ;
  ushort* vpT  = kp + SZ;                       // v-projection, transposed [(b,h,d), k]; later reused as h1
  ushort* Wb   = vpT + SZ;
  float*  zinv = (float*)(Wb + 6 * (size_t)262144);
  ushort* attn = Qb;
  ushort* outb = Kb;
  ushort* h1   = vpT;

  k_cvt<<<dim3(17920), dim3(256), 0, stream>>>(Q, K, Wq, Wk, Wv, Wo, W1, W2, Qb, Kb, Wb);
  k_gemm_qkv<<<dim3(128, 4, 3), dim3(256), 0, stream>>>(Qb, Kb, Wb, bq, bk, bv, qp, vpT);
  k_z<<<dim3(512), dim3(256), 0, stream>>>(qp, kp, zinv);
  k_attn<<<dim3(512), dim3(256), 0, stream>>>(qp, kp, vpT, zinv, attn);
  k_gemm<1><<<dim3(128, 4), dim3(256), 0, stream>>>(attn, Wb + 3*(size_t)262144, bo, Q, out, outb);
  k_gemm<2><<<dim3(128, 4), dim3(256), 0, stream>>>(outb, Wb + 4*(size_t)262144, b1, nullptr, nullptr, h1);
  k_gemm<3><<<dim3(128, 4), dim3(256), 0, stream>>>(h1, Wb + 5*(size_t)262144, b2, nullptr, out, nullptr);
}

// Round 4
// 165.874 us; speedup vs baseline: 1.2389x; 1.0908x over previous
//
#include <hip/hip_runtime.h>
#include <stdint.h>

// MAB block: B=32, N=512, D=512, H=8, dh=64.  M = B*N = 16384.
#define SCALE_ 0.044194173824159216f

typedef __attribute__((ext_vector_type(8))) short bf16x8;
typedef __attribute__((ext_vector_type(4))) float f32x4;

__device__ __forceinline__ ushort f2b(float f) {
  union { float f; uint32_t u; } v; v.f = f;
  return (ushort)((v.u + 0x7fffu + ((v.u >> 16) & 1u)) >> 16);  // RNE
}
__device__ __forceinline__ uint32_t cvtpk(float lo, float hi) {
  uint32_t r; asm("v_cvt_pk_bf16_f32 %0, %1, %2" : "=v"(r) : "v"(lo), "v"(hi)); return r;
}
__device__ __forceinline__ void gld16(void* lds, const void* g) {
  __builtin_amdgcn_global_load_lds(
      (const __attribute__((address_space(1))) uint32_t*)g,
      (__attribute__((address_space(3))) uint32_t*)lds, 16, 0, 0);
}

// ---------------- fp32 -> bf16 convert (Q, K, 6 weights) ----------------
__global__ __launch_bounds__(256)
void k_cvt(const float* __restrict__ Q, const float* __restrict__ K,
           const float* __restrict__ w0, const float* __restrict__ w1,
           const float* __restrict__ w2, const float* __restrict__ w3,
           const float* __restrict__ w4, const float* __restrict__ w5,
           ushort* __restrict__ Qb, ushort* __restrict__ Kb, ushort* __restrict__ Wb)
{
  const long long NQ = 8388608LL, NW = 262144LL;
  long long i = ((long long)blockIdx.x * 256 + threadIdx.x) * 4;
  const float* src; ushort* dst; long long off;
  if (i < NQ)        { src = Q; dst = Qb; off = i; }
  else if (i < 2*NQ) { src = K; dst = Kb; off = i - NQ; }
  else {
    long long j = i - 2*NQ; int seg = (int)(j / NW); off = j - (long long)seg * NW;
    switch (seg) { case 0: src = w0; break; case 1: src = w1; break; case 2: src = w2; break;
                   case 3: src = w3; break; case 4: src = w4; break; default: src = w5; }
    dst = Wb + (size_t)seg * NW;
  }
  float4 v = *(const float4*)(src + off);
  ushort4 o = make_ushort4(f2b(v.x), f2b(v.y), f2b(v.z), f2b(v.w));
  *(ushort4*)(dst + off) = o;
}

// ---------------- GEMM C = A(bf16,[M,512]) @ Bw(bf16,[512,512])^T ----------------
// 256x128 tile, BK=64, 512 threads (8 waves = 4M x 2N, per-wave 64x64).
// Triple-buffered LDS (3 x 48KB), counted vmcnt(6) + ONE s_barrier per K-tile,
// st_16x32 XOR swizzle (pre-swizzled global source, linear gld_lds dest, XOR'd reads).
// EPI: 0 = bias->bf16  1 = Q + (acc+bias) -> f32 + bf16  2 = relu->bf16
//      3 = out += acc+bias  4 = v-projection: write transposed vpT[(b,h,d),k]
template<int EPI>
__device__ __forceinline__ void gemm_body(const ushort* __restrict__ A, const ushort* __restrict__ Bw,
                                          const float* __restrict__ bias, const float* __restrict__ extra,
                                          float* __restrict__ outf, ushort* __restrict__ outb,
                                          char* lds, int m0, int n0)
{
  const int t = threadIdx.x;           // 0..511
  const int w = t >> 6, lane = t & 63;
  const int wm = w >> 1, wn = w & 1;   // 4M x 2N wave grid
  const int rA = lane & 15, g = lane >> 4;

  // ---- staging plan: per K-tile 48KB: A region [0,32768) = 256 rows x 128B,
  //      B region [32768,49152) = 128 rows x 128B.  16B chunks, linear LDS dest,
  //      source address inverse-swizzled (st_16x32: byte ^= ((byte>>9)&1)<<5).
  const ushort* srcA[4]; int ldsA[4];
#pragma unroll
  for (int j = 0; j < 4; j++) {
    int L = (t + j*512) * 16;
    int U = L ^ (((L >> 9) & 1) << 5);
    srcA[j] = A + (size_t)(m0 + (U >> 7))*512 + ((U & 127) >> 1);
    ldsA[j] = L;
  }
  const ushort* srcB[2]; int ldsB[2];
#pragma unroll
  for (int j = 0; j < 2; j++) {
    int L = (t + j*512) * 16;
    int U = L ^ (((L >> 9) & 1) << 5);
    srcB[j] = Bw + (size_t)(n0 + (U >> 7))*512 + ((U & 127) >> 1);
    ldsB[j] = 32768 + L;
  }

#define STAGE(ti) do { \
    char* bb_ = lds + ((ti) % 3) * 49152; \
    _Pragma("unroll") \
    for (int j = 0; j < 4; j++) gld16(bb_ + ldsA[j], srcA[j] + (ti)*64); \
    _Pragma("unroll") \
    for (int j = 0; j < 2; j++) gld16(bb_ + ldsB[j], srcB[j] + (ti)*64); } while (0)

  STAGE(0);
  STAGE(1);

  f32x4 acc[4][4] = {};
  for (int i = 0; i < 8; i++) {
    if (i < 7) asm volatile("s_waitcnt vmcnt(6)" ::: "memory");
    else       asm volatile("s_waitcnt vmcnt(0)" ::: "memory");
    __builtin_amdgcn_s_barrier();
    __builtin_amdgcn_sched_barrier(0);
    if (i < 6) STAGE(i + 2);
    const char* bufc = lds + (i % 3) * 49152;
#pragma unroll
    for (int ks = 0; ks < 2; ks++) {
      bf16x8 af[4], bfr[4];
#pragma unroll
      for (int m = 0; m < 4; m++) {
        int row = wm*64 + m*16 + rA;
        int off = row*128 + ks*64 + g*16;
        off ^= (row & 4) << 3;
        af[m] = *(const bf16x8*)(bufc + off);
      }
#pragma unroll
      for (int n = 0; n < 4; n++) {
        int row = wn*64 + n*16 + rA;
        int off = 32768 + row*128 + ks*64 + g*16;
        off ^= (row & 4) << 3;
        bfr[n] = *(const bf16x8*)(bufc + off);
      }
      __builtin_amdgcn_s_setprio(1);
#pragma unroll
      for (int m = 0; m < 4; m++)
#pragma unroll
        for (int n = 0; n < 4; n++)
          acc[m][n] = __builtin_amdgcn_mfma_f32_16x16x32_bf16(af[m], bfr[n], acc[m][n], 0, 0, 0);
      __builtin_amdgcn_s_setprio(0);
    }
  }
#undef STAGE

#pragma unroll
  for (int m = 0; m < 4; m++)
#pragma unroll
    for (int n = 0; n < 4; n++) {
      int col = n0 + wn*64 + n*16 + rA;
      float bb = bias[col];
      if (EPI == 4) {
        // transposed write: C[row=k, col=h*64+d] -> vpT[(b*8+h)*64+d][k], 4 k packed
        int b = m0 >> 9, k0 = m0 & 511;
        int hh = col >> 6, dl = col & 63;
        int kg = k0 + wm*64 + m*16 + g*4;
        float v0 = acc[m][n][0] + bb, v1 = acc[m][n][1] + bb;
        float v2 = acc[m][n][2] + bb, v3 = acc[m][n][3] + bb;
        uint2 pk;
        pk.x = (uint32_t)f2b(v0) | ((uint32_t)f2b(v1) << 16);
        pk.y = (uint32_t)f2b(v2) | ((uint32_t)f2b(v3) << 16);
        *(uint2*)(outb + ((size_t)((b*8 + hh)*64 + dl)*512 + kg)) = pk;
      } else {
#pragma unroll
        for (int r = 0; r < 4; r++) {
          int row = m0 + wm*64 + m*16 + g*4 + r;
          size_t idx = (size_t)row*512 + col;
          float v = acc[m][n][r] + bb;
          if (EPI == 0)      outb[idx] = f2b(v);
          else if (EPI == 1) { float o = extra[idx] + v; outf[idx] = o; outb[idx] = f2b(o); }
          else if (EPI == 2) outb[idx] = f2b(v > 0.f ? v : 0.f);
          else               outf[idx] += v;
        }
      }
    }
}

template<int EPI>
__global__ __launch_bounds__(512, 2)
void k_gemm(const ushort* __restrict__ A, const ushort* __restrict__ Bw,
            const float* __restrict__ bias, const float* __restrict__ extra,
            float* __restrict__ outf, ushort* __restrict__ outb)
{
  __shared__ __align__(16) char lds[3*49152];   // 144 KB
  gemm_body<EPI>(A, Bw, bias, extra, outf, outb, lds, blockIdx.x*256, blockIdx.y*128);
}

// fused qkv projection; z=2 (v) writes transposed vpT directly
__global__ __launch_bounds__(512, 2)
void k_gemm_qkv(const ushort* __restrict__ Qb, const ushort* __restrict__ Kb,
                const ushort* __restrict__ Wb, const float* __restrict__ bq,
                const float* __restrict__ bk, const float* __restrict__ bvv,
                ushort* __restrict__ qkout, ushort* __restrict__ vpT)
{
  __shared__ __align__(16) char lds[3*49152];
  int z = blockIdx.z;
  if (z == 2) {
    gemm_body<4>(Kb, Wb + 2*(size_t)262144, bvv, nullptr, nullptr,
                 vpT, lds, blockIdx.x*256, blockIdx.y*128);
  } else {
    const ushort* A = (z == 0) ? Qb : Kb;
    const float* bias = (z == 0) ? bq : bk;
    gemm_body<0>(A, Wb + (size_t)z*262144, bias, nullptr, nullptr,
                 qkout + (size_t)z*8388608, lds, blockIdx.x*256, blockIdx.y*128);
  }
}

// ---------------- K2: zinv[bh,k] = 1/sum_q exp(s*scale) ----------------
__global__ __launch_bounds__(256, 2)
void k_z(const ushort* __restrict__ qp, const ushort* __restrict__ kp, float* __restrict__ zinv)
{
  __shared__ __align__(16) ushort qt[2*8192];   // 2 x [128 q][64 d] (swizzled), 32KB
  int bid = blockIdx.x;
  int bh = bid >> 1, kh = bid & 1;
  int b = bh >> 3, h = bh & 7;
  int t = threadIdx.x, w = t >> 6, lane = t & 63;
  int rA = lane & 15, g = lane >> 4;
  const ushort* qbase = qp + (size_t)(b*512)*512 + h*64;
  bf16x8 kf[4][2];
#pragma unroll
  for (int n = 0; n < 4; n++)
#pragma unroll
    for (int ks = 0; ks < 2; ks++)
      kf[n][ks] = *(const bf16x8*)(kp + (size_t)(b*512 + kh*256 + w*64 + n*16 + rA)*512 + h*64 + ks*32 + g*8);

#define Z_STAGE(buf, qb) do { \
    _Pragma("unroll") \
    for (int i = 0; i < 4; i++) { \
      int c = i*256 + w*64 + lane; \
      int row = c >> 3, sl = c & 7; \
      gld16((char*)qt + (buf)*16384 + i*4096 + w*1024, \
            qbase + (size_t)((qb)*128 + row)*512 + ((sl ^ (row & 7))*8)); } } while (0)

  Z_STAGE(0, 0);
  __syncthreads();
  float Zacc[4] = {0.f, 0.f, 0.f, 0.f};
  for (int qb = 0; qb < 4; qb++) {
    const int cur = qb & 1;
    if (qb < 3) Z_STAGE(cur ^ 1, qb + 1);
    const ushort* qtb = qt + cur*8192;
    f32x4 acc[8][4] = {};
#pragma unroll
    for (int ks = 0; ks < 2; ks++) {
      bf16x8 af[8];
#pragma unroll
      for (int m = 0; m < 8; m++) {
        int q = m*16 + rA;
        af[m] = *(const bf16x8*)(qtb + q*64 + (((ks*4 + g) ^ (q & 7))*8));
      }
      __builtin_amdgcn_s_setprio(1);
#pragma unroll
      for (int m = 0; m < 8; m++)
#pragma unroll
        for (int n = 0; n < 4; n++)
          acc[m][n] = __builtin_amdgcn_mfma_f32_16x16x32_bf16(af[m], kf[n][ks], acc[m][n], 0, 0, 0);
      __builtin_amdgcn_s_setprio(0);
    }
#pragma unroll
    for (int m = 0; m < 8; m++)
#pragma unroll
      for (int n = 0; n < 4; n++) {
        float s = 0.f;
#pragma unroll
        for (int r = 0; r < 4; r++) s += __expf(acc[m][n][r] * SCALE_);
        Zacc[n] += s;
      }
    __syncthreads();
  }
#undef Z_STAGE
#pragma unroll
  for (int n = 0; n < 4; n++) {
    float v = Zacc[n];
    v += __shfl_xor(v, 16);
    v += __shfl_xor(v, 32);
    if (lane < 16) zinv[(size_t)bh*512 + kh*256 + w*64 + n*16 + lane] = 1.0f / v;
  }
}

// ---------------- K3: attn = (exp(QK^T*scale)*zinv) @ V ----------------
__global__ __launch_bounds__(256, 2)
void k_attn(const ushort* __restrict__ qp, const ushort* __restrict__ kp,
            const ushort* __restrict__ vpT, const float* __restrict__ zinv,
            ushort* __restrict__ attn)
{
  __shared__ __align__(16) ushort kt2[2*4096];  // 2 x [64 k][64 d] swizzled, 16KB
  __shared__ __align__(16) ushort vt2[2*4096];  // 2 x [64 d][64 k] swizzled, 16KB
  __shared__ __align__(16) ushort P[4*4096];    // per-wave [64 q][64 k] swizzled, 32KB
  __shared__ float zl[512];
  int bid = blockIdx.x;
  int bh = bid >> 1, qh = bid & 1;
  int b = bh >> 3, h = bh & 7;
  int t = threadIdx.x, w = t >> 6, lane = t & 63;
  int rA = lane & 15, g = lane >> 4;
  const ushort* kbase = kp + (size_t)(b*512)*512 + h*64;
  const ushort* vbase = vpT + (size_t)bh*64*512;
  ushort* Pw = P + w*4096;
  bf16x8 qf[4][2];
#pragma unroll
  for (int m = 0; m < 4; m++)
#pragma unroll
    for (int ks = 0; ks < 2; ks++)
      qf[m][ks] = *(const bf16x8*)(qp + (size_t)(b*512 + qh*256 + w*64 + m*16 + rA)*512 + h*64 + ks*32 + g*8);

#define A_STAGE(buf, kc) do { \
    _Pragma("unroll") \
    for (int i = 0; i < 2; i++) { \
      int c = i*256 + w*64 + lane; \
      { int k = c >> 3, sl = c & 7; \
        gld16((char*)kt2 + (buf)*8192 + i*4096 + w*1024, \
              kbase + (size_t)((kc)*64 + k)*512 + ((sl ^ (k & 7))*8)); } \
      { int d = c >> 3, sl = c & 7; \
        gld16((char*)vt2 + (buf)*8192 + i*4096 + w*1024, \
              vbase + (size_t)d*512 + (kc)*64 + ((sl ^ (d & 7))*8)); } } } while (0)

  A_STAGE(0, 0);
  zl[t]       = zinv[(size_t)bh*512 + t];
  zl[t + 256] = zinv[(size_t)bh*512 + t + 256];
  __syncthreads();
  f32x4 oacc[4][4] = {};
  for (int kc = 0; kc < 8; kc++) {
    const int cur = kc & 1;
    if (kc < 7) A_STAGE(cur ^ 1, kc + 1);
    const ushort* ktb = kt2 + cur*4096;
    const ushort* vtb = vt2 + cur*4096;
#pragma unroll
    for (int knh = 0; knh < 2; knh++) {
      f32x4 sacc[2][4] = {};
#pragma unroll
      for (int ks = 0; ks < 2; ks++) {
        bf16x8 kfr[2];
#pragma unroll
        for (int kn2 = 0; kn2 < 2; kn2++) {
          int k = (knh*2 + kn2)*16 + rA;
          kfr[kn2] = *(const bf16x8*)(ktb + k*64 + (((ks*4 + g) ^ (k & 7))*8));
        }
        __builtin_amdgcn_s_setprio(1);
#pragma unroll
        for (int kn2 = 0; kn2 < 2; kn2++)
#pragma unroll
          for (int m = 0; m < 4; m++)
            sacc[kn2][m] = __builtin_amdgcn_mfma_f32_16x16x32_bf16(kfr[kn2], qf[m][ks], sacc[kn2][m], 0, 0, 0);
        __builtin_amdgcn_s_setprio(0);
      }
#pragma unroll
      for (int kn2 = 0; kn2 < 2; kn2++) {
        int kn = knh*2 + kn2;
        f32x4 zv = *(const f32x4*)&zl[kc*64 + kn*16 + g*4];
#pragma unroll
        for (int m = 0; m < 4; m++) {
          float e0 = __expf(sacc[kn2][m][0] * SCALE_) * zv[0];
          float e1 = __expf(sacc[kn2][m][1] * SCALE_) * zv[1];
          float e2 = __expf(sacc[kn2][m][2] * SCALE_) * zv[2];
          float e3 = __expf(sacc[kn2][m][3] * SCALE_) * zv[3];
          uint2 pk; pk.x = cvtpk(e0, e1); pk.y = cvtpk(e2, e3);
          int q = m*16 + rA;
          int kb2 = kn*32 + g*8;
          *(uint2*)((char*)Pw + q*128 + (kb2 ^ ((q & 7) << 4))) = pk;
        }
      }
    }
#pragma unroll
    for (int ks = 0; ks < 2; ks++) {
      bf16x8 pa[4], vb[4];
#pragma unroll
      for (int m = 0; m < 4; m++) {
        int q = m*16 + rA;
        pa[m] = *(const bf16x8*)((const char*)Pw + q*128 + ((ks*64 + g*16) ^ ((q & 7) << 4)));
      }
#pragma unroll
      for (int n = 0; n < 4; n++) {
        int d = n*16 + rA;
        vb[n] = *(const bf16x8*)((const char*)vtb + d*128 + ((ks*64 + g*16) ^ ((d & 7) << 4)));
      }
      __builtin_amdgcn_s_setprio(1);
#pragma unroll
      for (int m = 0; m < 4; m++)
#pragma unroll
        for (int n = 0; n < 4; n++)
          oacc[m][n] = __builtin_amdgcn_mfma_f32_16x16x32_bf16(pa[m], vb[n], oacc[m][n], 0, 0, 0);
      __builtin_amdgcn_s_setprio(0);
    }
    __syncthreads();
  }
#undef A_STAGE
#pragma unroll
  for (int m = 0; m < 4; m++)
#pragma unroll
    for (int n = 0; n < 4; n++)
#pragma unroll
      for (int r = 0; r < 4; r++) {
        int q = qh*256 + w*64 + m*16 + g*4 + r;
        int dcol = h*64 + n*16 + rA;
        attn[(size_t)(b*512 + q)*512 + dcol] = f2b(oacc[m][n][r]);
      }
}

// ---------------- host launcher ----------------
extern "C" void kernel_launch(void* const* d_in, const int* in_sizes, int n_in,
                              void* d_out, int out_size, void* d_ws, size_t ws_size,
                              hipStream_t stream) {
  const float* Q  = (const float*)d_in[0];
  const float* K  = (const float*)d_in[1];
  const float* Wq = (const float*)d_in[2];
  const float* bq = (const float*)d_in[3];
  const float* Wk = (const float*)d_in[4];
  const float* bk = (const float*)d_in[5];
  const float* Wv = (const float*)d_in[6];
  const float* bv = (const float*)d_in[7];
  const float* Wo = (const float*)d_in[8];
  const float* bo = (const float*)d_in[9];
  const float* W1 = (const float*)d_in[10];
  const float* b1 = (const float*)d_in[11];
  const float* W2 = (const float*)d_in[12];
  const float* b2 = (const float*)d_in[13];
  float* out = (float*)d_out;

  const size_t SZ = (size_t)16384 * 512;
  ushort* Qb   = (ushort*)d_ws;                 // later reused as attn
  ushort* Kb   = Qb + SZ;                       // later reused as outb
  ushort* qp   = Kb + SZ;
  ushort* kp   = qp + SZ;
  ushort* vpT  = kp + SZ;                       // v-projection, transposed; later reused as h1
  ushort* Wb   = vpT + SZ;
  float*  zinv = (float*)(Wb + 6 * (size_t)262144);
  ushort* attn = Qb;
  ushort* outb = Kb;
  ushort* h1   = vpT;

  k_cvt<<<dim3(17920), dim3(256), 0, stream>>>(Q, K, Wq, Wk, Wv, Wo, W1, W2, Qb, Kb, Wb);
  k_gemm_qkv<<<dim3(64, 4, 3), dim3(512), 0, stream>>>(Qb, Kb, Wb, bq, bk, bv, qp, vpT);
  k_z<<<dim3(512), dim3(256), 0, stream>>>(qp, kp, zinv);
  k_attn<<<dim3(512), dim3(256), 0, stream>>>(qp, kp, vpT, zinv, attn);
  k_gemm<1><<<dim3(64, 4), dim3(512), 0, stream>>>(attn, Wb + 3*(size_t)262144, bo, Q, out, outb);
  k_gemm<2><<<dim3(64, 4), dim3(512), 0, stream>>>(outb, Wb + 4*(size_t)262144, b1, nullptr, nullptr, h1);
  k_gemm<3><<<dim3(64, 4), dim3(512), 0, stream>>>(h1, Wb + 5*(size_t)262144, b2, nullptr, out, nullptr);
}

// Round 5
// 164.738 us; speedup vs baseline: 1.2475x; 1.0069x over previous
//
#include <hip/hip_runtime.h>
#include <stdint.h>

// MAB block: B=32, N=512, D=512, H=8, dh=64.  M = B*N = 16384.
#define SCALE_ 0.044194173824159216f

typedef __attribute__((ext_vector_type(8))) short bf16x8;
typedef __attribute__((ext_vector_type(4))) float f32x4;

__device__ __forceinline__ ushort f2b(float f) {
  union { float f; uint32_t u; } v; v.f = f;
  return (ushort)((v.u + 0x7fffu + ((v.u >> 16) & 1u)) >> 16);  // RNE
}
__device__ __forceinline__ uint32_t cvtpk(float lo, float hi) {
  uint32_t r; asm("v_cvt_pk_bf16_f32 %0, %1, %2" : "=v"(r) : "v"(lo), "v"(hi)); return r;
}
__device__ __forceinline__ void gld16(void* lds, const void* g) {
  __builtin_amdgcn_global_load_lds(
      (const __attribute__((address_space(1))) uint32_t*)g,
      (__attribute__((address_space(3))) uint32_t*)lds, 16, 0, 0);
}

// ---------------- fp32 -> bf16 convert (Q, K, 6 weights) ----------------
__global__ __launch_bounds__(256)
void k_cvt(const float* __restrict__ Q, const float* __restrict__ K,
           const float* __restrict__ w0, const float* __restrict__ w1,
           const float* __restrict__ w2, const float* __restrict__ w3,
           const float* __restrict__ w4, const float* __restrict__ w5,
           ushort* __restrict__ Qb, ushort* __restrict__ Kb, ushort* __restrict__ Wb)
{
  const long long NQ = 8388608LL, NW = 262144LL;
  long long i = ((long long)blockIdx.x * 256 + threadIdx.x) * 4;
  const float* src; ushort* dst; long long off;
  if (i < NQ)        { src = Q; dst = Qb; off = i; }
  else if (i < 2*NQ) { src = K; dst = Kb; off = i - NQ; }
  else {
    long long j = i - 2*NQ; int seg = (int)(j / NW); off = j - (long long)seg * NW;
    switch (seg) { case 0: src = w0; break; case 1: src = w1; break; case 2: src = w2; break;
                   case 3: src = w3; break; case 4: src = w4; break; default: src = w5; }
    dst = Wb + (size_t)seg * NW;
  }
  float4 v = *(const float4*)(src + off);
  ushort4 o = make_ushort4(f2b(v.x), f2b(v.y), f2b(v.z), f2b(v.w));
  *(ushort4*)(dst + off) = o;
}

// ---------------- GEMM C = A(bf16,[M,512]) @ Bw(bf16,[512,512])^T ----------------
// 256x128 tile, BK=64, 512 threads (8 waves = 4M x 2N, per-wave 64x64).
// Triple-buffered LDS (3 x 48KB), counted vmcnt(6) + ONE s_barrier per K-tile.
// 3-bit slot swizzle (G4): byte ^= (row&7)<<4 — inverse-swizzled global source,
// linear gld_lds dest, XOR'd fragment reads.  16 consecutive rows -> 8 slots,
// 2 lanes/slot = conflict-free (m136).
// EPI: 0 = bias->bf16  1 = Q + (acc+bias) -> f32 + bf16  2 = relu->bf16
//      3 = out += acc+bias  4 = v-projection: write transposed vpT[(b,h,d),k]
template<int EPI>
__device__ __forceinline__ void gemm_body(const ushort* __restrict__ A, const ushort* __restrict__ Bw,
                                          const float* __restrict__ bias, const float* __restrict__ extra,
                                          float* __restrict__ outf, ushort* __restrict__ outb,
                                          char* lds, int m0, int n0)
{
  const int t = threadIdx.x;           // 0..511
  const int w = t >> 6, lane = t & 63;
  const int wm = w >> 1, wn = w & 1;   // 4M x 2N wave grid
  const int rA = lane & 15, g = lane >> 4;

  // staging: per K-tile 48KB: A [0,32768) = 256 rows x 128B, B [32768,49152) = 128 x 128B.
  // Inverse-swizzle source: U = L ^ (((L>>7)&7)<<4)  (involution; bits 4-6 sub-row).
  const ushort* srcA[4]; int ldsA[4];
#pragma unroll
  for (int j = 0; j < 4; j++) {
    int L = (t + j*512) * 16;
    int U = L ^ (((L >> 7) & 7) << 4);
    srcA[j] = A + (size_t)(m0 + (U >> 7))*512 + ((U & 127) >> 1);
    ldsA[j] = L;
  }
  const ushort* srcB[2]; int ldsB[2];
#pragma unroll
  for (int j = 0; j < 2; j++) {
    int L = (t + j*512) * 16;
    int U = L ^ (((L >> 7) & 7) << 4);
    srcB[j] = Bw + (size_t)(n0 + (U >> 7))*512 + ((U & 127) >> 1);
    ldsB[j] = 32768 + L;
  }

#define STAGE(ti) do { \
    char* bb_ = lds + ((ti) % 3) * 49152; \
    _Pragma("unroll") \
    for (int j = 0; j < 4; j++) gld16(bb_ + ldsA[j], srcA[j] + (ti)*64); \
    _Pragma("unroll") \
    for (int j = 0; j < 2; j++) gld16(bb_ + ldsB[j], srcB[j] + (ti)*64); } while (0)

  STAGE(0);
  STAGE(1);

  f32x4 acc[4][4] = {};
  for (int i = 0; i < 8; i++) {
    if (i < 7) asm volatile("s_waitcnt vmcnt(6)" ::: "memory");
    else       asm volatile("s_waitcnt vmcnt(0)" ::: "memory");
    __builtin_amdgcn_s_barrier();
    __builtin_amdgcn_sched_barrier(0);
    if (i < 6) STAGE(i + 2);
    const char* bufc = lds + (i % 3) * 49152;
#pragma unroll
    for (int ks = 0; ks < 2; ks++) {
      bf16x8 af[4], bfr[4];
#pragma unroll
      for (int m = 0; m < 4; m++) {
        int row = wm*64 + m*16 + rA;
        int off = (row*128 + ks*64 + g*16) ^ ((row & 7) << 4);
        af[m] = *(const bf16x8*)(bufc + off);
      }
#pragma unroll
      for (int n = 0; n < 4; n++) {
        int row = wn*64 + n*16 + rA;
        int off = 32768 + ((row*128 + ks*64 + g*16) ^ ((row & 7) << 4));
        bfr[n] = *(const bf16x8*)(bufc + off);
      }
      __builtin_amdgcn_s_setprio(1);
#pragma unroll
      for (int m = 0; m < 4; m++)
#pragma unroll
        for (int n = 0; n < 4; n++)
          acc[m][n] = __builtin_amdgcn_mfma_f32_16x16x32_bf16(af[m], bfr[n], acc[m][n], 0, 0, 0);
      __builtin_amdgcn_s_setprio(0);
    }
  }
#undef STAGE

#pragma unroll
  for (int m = 0; m < 4; m++)
#pragma unroll
    for (int n = 0; n < 4; n++) {
      int col = n0 + wn*64 + n*16 + rA;
      float bb = bias[col];
      if (EPI == 4) {
        // transposed write: C[row=k, col=h*64+d] -> vpT[(b*8+h)*64+d][k], 4 k packed
        int b = m0 >> 9, k0 = m0 & 511;
        int hh = col >> 6, dl = col & 63;
        int kg = k0 + wm*64 + m*16 + g*4;
        float v0 = acc[m][n][0] + bb, v1 = acc[m][n][1] + bb;
        float v2 = acc[m][n][2] + bb, v3 = acc[m][n][3] + bb;
        uint2 pk;
        pk.x = (uint32_t)f2b(v0) | ((uint32_t)f2b(v1) << 16);
        pk.y = (uint32_t)f2b(v2) | ((uint32_t)f2b(v3) << 16);
        *(uint2*)(outb + ((size_t)((b*8 + hh)*64 + dl)*512 + kg)) = pk;
      } else {
#pragma unroll
        for (int r = 0; r < 4; r++) {
          int row = m0 + wm*64 + m*16 + g*4 + r;
          size_t idx = (size_t)row*512 + col;
          float v = acc[m][n][r] + bb;
          if (EPI == 0)      outb[idx] = f2b(v);
          else if (EPI == 1) { float o = extra[idx] + v; outf[idx] = o; outb[idx] = f2b(o); }
          else if (EPI == 2) outb[idx] = f2b(v > 0.f ? v : 0.f);
          else               outf[idx] += v;
        }
      }
    }
}

template<int EPI>
__global__ __launch_bounds__(512, 2)
void k_gemm(const ushort* __restrict__ A, const ushort* __restrict__ Bw,
            const float* __restrict__ bias, const float* __restrict__ extra,
            float* __restrict__ outf, ushort* __restrict__ outb)
{
  __shared__ __align__(16) char lds[3*49152];   // 144 KB
  gemm_body<EPI>(A, Bw, bias, extra, outf, outb, lds, blockIdx.x*256, blockIdx.y*128);
}

// fused qkv projection; z=2 (v) writes transposed vpT directly
__global__ __launch_bounds__(512, 2)
void k_gemm_qkv(const ushort* __restrict__ Qb, const ushort* __restrict__ Kb,
                const ushort* __restrict__ Wb, const float* __restrict__ bq,
                const float* __restrict__ bk, const float* __restrict__ bvv,
                ushort* __restrict__ qkout, ushort* __restrict__ vpT)
{
  __shared__ __align__(16) char lds[3*49152];
  int z = blockIdx.z;
  if (z == 2) {
    gemm_body<4>(Kb, Wb + 2*(size_t)262144, bvv, nullptr, nullptr,
                 vpT, lds, blockIdx.x*256, blockIdx.y*128);
  } else {
    const ushort* A = (z == 0) ? Qb : Kb;
    const float* bias = (z == 0) ? bq : bk;
    gemm_body<0>(A, Wb + (size_t)z*262144, bias, nullptr, nullptr,
                 qkout + (size_t)z*8388608, lds, blockIdx.x*256, blockIdx.y*128);
  }
}

// ---------------- K2: zinv[bh,k] = 1/sum_q exp(s*scale) ----------------
__global__ __launch_bounds__(256, 2)
void k_z(const ushort* __restrict__ qp, const ushort* __restrict__ kp, float* __restrict__ zinv)
{
  __shared__ __align__(16) ushort qt[2*8192];   // 2 x [128 q][64 d] (swizzled), 32KB
  int bid = blockIdx.x;
  int bh = bid >> 1, kh = bid & 1;
  int b = bh >> 3, h = bh & 7;
  int t = threadIdx.x, w = t >> 6, lane = t & 63;
  int rA = lane & 15, g = lane >> 4;
  const ushort* qbase = qp + (size_t)(b*512)*512 + h*64;
  bf16x8 kf[4][2];
#pragma unroll
  for (int n = 0; n < 4; n++)
#pragma unroll
    for (int ks = 0; ks < 2; ks++)
      kf[n][ks] = *(const bf16x8*)(kp + (size_t)(b*512 + kh*256 + w*64 + n*16 + rA)*512 + h*64 + ks*32 + g*8);

#define Z_STAGE(buf, qb) do { \
    _Pragma("unroll") \
    for (int i = 0; i < 4; i++) { \
      int c = i*256 + w*64 + lane; \
      int row = c >> 3, sl = c & 7; \
      gld16((char*)qt + (buf)*16384 + i*4096 + w*1024, \
            qbase + (size_t)((qb)*128 + row)*512 + ((sl ^ (row & 7))*8)); } } while (0)

  Z_STAGE(0, 0);
  __syncthreads();
  float Zacc[4] = {0.f, 0.f, 0.f, 0.f};
  for (int qb = 0; qb < 4; qb++) {
    const int cur = qb & 1;
    if (qb < 3) Z_STAGE(cur ^ 1, qb + 1);
    const ushort* qtb = qt + cur*8192;
    f32x4 acc[8][4] = {};
#pragma unroll
    for (int ks = 0; ks < 2; ks++) {
      bf16x8 af[8];
#pragma unroll
      for (int m = 0; m < 8; m++) {
        int q = m*16 + rA;
        af[m] = *(const bf16x8*)(qtb + q*64 + (((ks*4 + g) ^ (q & 7))*8));
      }
      __builtin_amdgcn_s_setprio(1);
#pragma unroll
      for (int m = 0; m < 8; m++)
#pragma unroll
        for (int n = 0; n < 4; n++)
          acc[m][n] = __builtin_amdgcn_mfma_f32_16x16x32_bf16(af[m], kf[n][ks], acc[m][n], 0, 0, 0);
      __builtin_amdgcn_s_setprio(0);
    }
#pragma unroll
    for (int m = 0; m < 8; m++)
#pragma unroll
      for (int n = 0; n < 4; n++) {
        float s = 0.f;
#pragma unroll
        for (int r = 0; r < 4; r++) s += __expf(acc[m][n][r] * SCALE_);
        Zacc[n] += s;
      }
    __syncthreads();
  }
#undef Z_STAGE
#pragma unroll
  for (int n = 0; n < 4; n++) {
    float v = Zacc[n];
    v += __shfl_xor(v, 16);
    v += __shfl_xor(v, 32);
    if (lane < 16) zinv[(size_t)bh*512 + kh*256 + w*64 + n*16 + lane] = 1.0f / v;
  }
}

// ---------------- K3: attn = (exp(QK^T*scale)*zinv) @ V ----------------
__global__ __launch_bounds__(256, 2)
void k_attn(const ushort* __restrict__ qp, const ushort* __restrict__ kp,
            const ushort* __restrict__ vpT, const float* __restrict__ zinv,
            ushort* __restrict__ attn)
{
  __shared__ __align__(16) ushort kt2[2*4096];  // 2 x [64 k][64 d] swizzled, 16KB
  __shared__ __align__(16) ushort vt2[2*4096];  // 2 x [64 d][64 k] swizzled, 16KB
  __shared__ __align__(16) ushort P[4*4096];    // per-wave [64 q][64 k] swizzled, 32KB
  __shared__ float zl[512];
  int bid = blockIdx.x;
  int bh = bid >> 1, qh = bid & 1;
  int b = bh >> 3, h = bh & 7;
  int t = threadIdx.x, w = t >> 6, lane = t & 63;
  int rA = lane & 15, g = lane >> 4;
  const ushort* kbase = kp + (size_t)(b*512)*512 + h*64;
  const ushort* vbase = vpT + (size_t)bh*64*512;
  ushort* Pw = P + w*4096;
  bf16x8 qf[4][2];
#pragma unroll
  for (int m = 0; m < 4; m++)
#pragma unroll
    for (int ks = 0; ks < 2; ks++)
      qf[m][ks] = *(const bf16x8*)(qp + (size_t)(b*512 + qh*256 + w*64 + m*16 + rA)*512 + h*64 + ks*32 + g*8);

#define A_STAGE(buf, kc) do { \
    _Pragma("unroll") \
    for (int i = 0; i < 2; i++) { \
      int c = i*256 + w*64 + lane; \
      { int k = c >> 3, sl = c & 7; \
        gld16((char*)kt2 + (buf)*8192 + i*4096 + w*1024, \
              kbase + (size_t)((kc)*64 + k)*512 + ((sl ^ (k & 7))*8)); } \
      { int d = c >> 3, sl = c & 7; \
        gld16((char*)vt2 + (buf)*8192 + i*4096 + w*1024, \
              vbase + (size_t)d*512 + (kc)*64 + ((sl ^ (d & 7))*8)); } } } while (0)

  A_STAGE(0, 0);
  zl[t]       = zinv[(size_t)bh*512 + t];
  zl[t + 256] = zinv[(size_t)bh*512 + t + 256];
  __syncthreads();
  f32x4 oacc[4][4] = {};
  for (int kc = 0; kc < 8; kc++) {
    const int cur = kc & 1;
    if (kc < 7) A_STAGE(cur ^ 1, kc + 1);
    const ushort* ktb = kt2 + cur*4096;
    const ushort* vtb = vt2 + cur*4096;
#pragma unroll
    for (int knh = 0; knh < 2; knh++) {
      f32x4 sacc[2][4] = {};
#pragma unroll
      for (int ks = 0; ks < 2; ks++) {
        bf16x8 kfr[2];
#pragma unroll
        for (int kn2 = 0; kn2 < 2; kn2++) {
          int k = (knh*2 + kn2)*16 + rA;
          kfr[kn2] = *(const bf16x8*)(ktb + k*64 + (((ks*4 + g) ^ (k & 7))*8));
        }
        __builtin_amdgcn_s_setprio(1);
#pragma unroll
        for (int kn2 = 0; kn2 < 2; kn2++)
#pragma unroll
          for (int m = 0; m < 4; m++)
            sacc[kn2][m] = __builtin_amdgcn_mfma_f32_16x16x32_bf16(kfr[kn2], qf[m][ks], sacc[kn2][m], 0, 0, 0);
        __builtin_amdgcn_s_setprio(0);
      }
#pragma unroll
      for (int kn2 = 0; kn2 < 2; kn2++) {
        int kn = knh*2 + kn2;
        f32x4 zv = *(const f32x4*)&zl[kc*64 + kn*16 + g*4];
#pragma unroll
        for (int m = 0; m < 4; m++) {
          float e0 = __expf(sacc[kn2][m][0] * SCALE_) * zv[0];
          float e1 = __expf(sacc[kn2][m][1] * SCALE_) * zv[1];
          float e2 = __expf(sacc[kn2][m][2] * SCALE_) * zv[2];
          float e3 = __expf(sacc[kn2][m][3] * SCALE_) * zv[3];
          uint2 pk; pk.x = cvtpk(e0, e1); pk.y = cvtpk(e2, e3);
          int q = m*16 + rA;
          int kb2 = kn*32 + g*8;
          *(uint2*)((char*)Pw + q*128 + (kb2 ^ ((q & 7) << 4))) = pk;
        }
      }
    }
#pragma unroll
    for (int ks = 0; ks < 2; ks++) {
      bf16x8 pa[4], vb[4];
#pragma unroll
      for (int m = 0; m < 4; m++) {
        int q = m*16 + rA;
        pa[m] = *(const bf16x8*)((const char*)Pw + q*128 + ((ks*64 + g*16) ^ ((q & 7) << 4)));
      }
#pragma unroll
      for (int n = 0; n < 4; n++) {
        int d = n*16 + rA;
        vb[n] = *(const bf16x8*)((const char*)vtb + d*128 + ((ks*64 + g*16) ^ ((d & 7) << 4)));
      }
      __builtin_amdgcn_s_setprio(1);
#pragma unroll
      for (int m = 0; m < 4; m++)
#pragma unroll
        for (int n = 0; n < 4; n++)
          oacc[m][n] = __builtin_amdgcn_mfma_f32_16x16x32_bf16(pa[m], vb[n], oacc[m][n], 0, 0, 0);
      __builtin_amdgcn_s_setprio(0);
    }
    __syncthreads();
  }
#undef A_STAGE
#pragma unroll
  for (int m = 0; m < 4; m++)
#pragma unroll
    for (int n = 0; n < 4; n++)
#pragma unroll
      for (int r = 0; r < 4; r++) {
        int q = qh*256 + w*64 + m*16 + g*4 + r;
        int dcol = h*64 + n*16 + rA;
        attn[(size_t)(b*512 + q)*512 + dcol] = f2b(oacc[m][n][r]);
      }
}

// ---------------- host launcher ----------------
extern "C" void kernel_launch(void* const* d_in, const int* in_sizes, int n_in,
                              void* d_out, int out_size, void* d_ws, size_t ws_size,
                              hipStream_t stream) {
  const float* Q  = (const float*)d_in[0];
  const float* K  = (const float*)d_in[1];
  const float* Wq = (const float*)d_in[2];
  const float* bq = (const float*)d_in[3];
  const float* Wk = (const float*)d_in[4];
  const float* bk = (const float*)d_in[5];
  const float* Wv = (const float*)d_in[6];
  const float* bv = (const float*)d_in[7];
  const float* Wo = (const float*)d_in[8];
  const float* bo = (const float*)d_in[9];
  const float* W1 = (const float*)d_in[10];
  const float* b1 = (const float*)d_in[11];
  const float* W2 = (const float*)d_in[12];
  const float* b2 = (const float*)d_in[13];
  float* out = (float*)d_out;

  const size_t SZ = (size_t)16384 * 512;
  ushort* Qb   = (ushort*)d_ws;                 // later reused as attn
  ushort* Kb   = Qb + SZ;                       // later reused as outb
  ushort* qp   = Kb + SZ;
  ushort* kp   = qp + SZ;
  ushort* vpT  = kp + SZ;                       // v-projection, transposed; later reused as h1
  ushort* Wb   = vpT + SZ;
  float*  zinv = (float*)(Wb + 6 * (size_t)262144);
  ushort* attn = Qb;
  ushort* outb = Kb;
  ushort* h1   = vpT;

  k_cvt<<<dim3(17920), dim3(256), 0, stream>>>(Q, K, Wq, Wk, Wv, Wo, W1, W2, Qb, Kb, Wb);
  k_gemm_qkv<<<dim3(64, 4, 3), dim3(512), 0, stream>>>(Qb, Kb, Wb, bq, bk, bv, qp, vpT);
  k_z<<<dim3(512), dim3(256), 0, stream>>>(qp, kp, zinv);
  k_attn<<<dim3(512), dim3(256), 0, stream>>>(qp, kp, vpT, zinv, attn);
  k_gemm<1><<<dim3(64, 4), dim3(512), 0, stream>>>(attn, Wb + 3*(size_t)262144, bo, Q, out, outb);
  k_gemm<2><<<dim3(64, 4), dim3(512), 0, stream>>>(outb, Wb + 4*(size_t)262144, b1, nullptr, nullptr, h1);
  k_gemm<3><<<dim3(64, 4), dim3(512), 0, stream>>>(h1, Wb + 5*(size_t)262144, b2, nullptr, out, nullptr);
}